// Round 2
// baseline (2302.126 us; speedup 1.0000x reference)
//
#include <hip/hip_runtime.h>
#include <math.h>

#define B_   8
#define T_   16
#define N_   256
#define C_   1024
#define H_   16
#define HD_  64
#define K_   8
#define BT_  128
#define M_   (BT_*N_)   // 32768 rows

typedef __attribute__((ext_vector_type(8))) short short8;
typedef __attribute__((ext_vector_type(4))) float f32x4;

__device__ __forceinline__ unsigned short bf16_rne(float f) {
    unsigned u = __float_as_uint(f);
    return (unsigned short)((u + 0x7FFFu + ((u >> 16) & 1u)) >> 16);
}
__device__ __forceinline__ float bf16_tof(unsigned short h) {
    return __uint_as_float(((unsigned)h) << 16);
}
__device__ __forceinline__ void split8(const float* v, short8& h, short8& l) {
#pragma unroll
    for (int j = 0; j < 8; ++j) {
        unsigned short hb = bf16_rne(v[j]);
        h[j] = (short)hb;
        l[j] = (short)bf16_rne(v[j] - bf16_tof(hb));
    }
}
__device__ __forceinline__ void cvt8(const float* v, short8& h) {
#pragma unroll
    for (int j = 0; j < 8; ++j) h[j] = (short)bf16_rne(v[j]);
}

#define MFMA16(a, b, c) __builtin_amdgcn_mfma_f32_16x16x32_bf16(a, b, c, 0, 0, 0)

// ---------------------------------------------------------------------------
// expert sum
// ---------------------------------------------------------------------------
__global__ __launch_bounds__(256) void expert_sum_kernel(
    const float* __restrict__ qe, const float* __restrict__ ke,
    float* __restrict__ qsum, float* __restrict__ ksum)
{
    int idx = blockIdx.x * 256 + threadIdx.x;
    int which = idx >> 13;
    int kd = idx & 8191;
    const float* src = (which ? ke : qe) + (size_t)(kd >> 10) * C_ * C_ + (kd & (C_ - 1));
    float s = 0.f;
    for (int i = 0; i < C_; ++i) s += src[(size_t)i * C_];
    (which ? ksum : qsum)[kd] = s;
}

// ---------------------------------------------------------------------------
// dyn = softmax(y @ dyn_w.T + dyn_b)
// ---------------------------------------------------------------------------
__global__ __launch_bounds__(256) void dyn_kernel(
    const float* __restrict__ y, const float* __restrict__ dyn_w,
    const float* __restrict__ dyn_b, float* __restrict__ dyn)
{
    __shared__ float red[256];
    __shared__ float logits[K_];
    int row = blockIdx.x;
    int tid = threadIdx.x;
    const float* yr = y + (size_t)row * C_;
    float part[K_];
#pragma unroll
    for (int k = 0; k < K_; ++k) part[k] = 0.f;
    for (int c = tid; c < C_; c += 256) {
        float yv = yr[c];
#pragma unroll
        for (int k = 0; k < K_; ++k) part[k] += yv * dyn_w[k * C_ + c];
    }
    for (int k = 0; k < K_; ++k) {
        red[tid] = part[k];
        __syncthreads();
        for (int s = 128; s > 0; s >>= 1) {
            if (tid < s) red[tid] += red[tid + s];
            __syncthreads();
        }
        if (tid == 0) logits[k] = red[0] + dyn_b[k];
        __syncthreads();
    }
    if (tid == 0) {
        float m = logits[0];
#pragma unroll
        for (int k = 1; k < K_; ++k) m = fmaxf(m, logits[k]);
        float e[K_];
        float l = 0.f;
#pragma unroll
        for (int k = 0; k < K_; ++k) { e[k] = __expf(logits[k] - m); l += e[k]; }
        float rl = 1.f / l;
#pragma unroll
        for (int k = 0; k < K_; ++k) dyn[(size_t)row * K_ + k] = e[k] * rl;
    }
}

// ---------------------------------------------------------------------------
__global__ __launch_bounds__(256) void scale_kernel(
    const float* __restrict__ dyn, const float* __restrict__ qsum,
    const float* __restrict__ ksum, float* __restrict__ qs, float* __restrict__ ks)
{
    int row = blockIdx.x;
    int d = threadIdx.x * 4;
    float w[K_];
#pragma unroll
    for (int k = 0; k < K_; ++k) w[k] = dyn[(size_t)row * K_ + k];
    float4 aq = {0, 0, 0, 0}, ak = {0, 0, 0, 0};
#pragma unroll
    for (int k = 0; k < K_; ++k) {
        float4 q4 = *(const float4*)(qsum + k * C_ + d);
        float4 k4 = *(const float4*)(ksum + k * C_ + d);
        aq.x += w[k] * q4.x; aq.y += w[k] * q4.y; aq.z += w[k] * q4.z; aq.w += w[k] * q4.w;
        ak.x += w[k] * k4.x; ak.y += w[k] * k4.y; ak.z += w[k] * k4.z; ak.w += w[k] * k4.w;
    }
    *(float4*)(qs + (size_t)row * C_ + d) = aq;
    *(float4*)(ks + (size_t)row * C_ + d) = ak;
}

// ---------------------------------------------------------------------------
__global__ __launch_bounds__(256) void bcomb_kernel(
    const float* __restrict__ wv, const float* __restrict__ v_b,
    const float* __restrict__ bv, float* __restrict__ b_comb)
{
    __shared__ float red[256];
    int j = blockIdx.x, tid = threadIdx.x;
    float p = 0.f;
    for (int e = tid; e < C_; e += 256) p += wv[(size_t)j * C_ + e] * v_b[e];
    red[tid] = p;
    __syncthreads();
    for (int s = 128; s > 0; s >>= 1) {
        if (tid < s) red[tid] += red[tid + s];
        __syncthreads();
    }
    if (tid == 0) b_comb[j] = red[0] + bv[j];
}

// ---------------------------------------------------------------------------
// fp32 NN GEMM (only for 1024^3 W_comb = wv @ v_w)
// ---------------------------------------------------------------------------
__global__ __launch_bounds__(256) void gemm_f32_nn(
    const float* __restrict__ A, const float* __restrict__ Bm,
    float* __restrict__ D, int M, int N, int K)
{
    __shared__ float As[16][132];
    __shared__ float Bs[16][132];
    const int tid = threadIdx.x;
    const int m0 = blockIdx.x * 128;
    const int n0 = blockIdx.y * 128;
    const int tx = tid & 15, ty = tid >> 4;
    const int lr = tid >> 2;
    const int lc = (tid & 3) * 4;
    const int bc = tid >> 4;
    const int bn = (tid & 15) * 8;
    float acc[8][8];
#pragma unroll
    for (int i = 0; i < 8; ++i)
#pragma unroll
        for (int j = 0; j < 8; ++j) acc[i][j] = 0.f;

    for (int k0 = 0; k0 < K; k0 += 16) {
#pragma unroll
        for (int half = 0; half < 2; ++half) {
            int r = lr + half * 64;
            float4 a = *(const float4*)(A + (size_t)(m0 + r) * K + k0 + lc);
            As[lc + 0][r] = a.x; As[lc + 1][r] = a.y;
            As[lc + 2][r] = a.z; As[lc + 3][r] = a.w;
        }
        {
            const float* bp = Bm + (size_t)(k0 + bc) * N + n0 + bn;
            float4 b0 = *(const float4*)(bp);
            float4 b1 = *(const float4*)(bp + 4);
            *(float4*)&Bs[bc][bn] = b0;
            *(float4*)&Bs[bc][bn + 4] = b1;
        }
        __syncthreads();
#pragma unroll
        for (int kk = 0; kk < 16; ++kk) {
            float4 a0 = *(const float4*)&As[kk][ty * 4];
            float4 a1 = *(const float4*)&As[kk][64 + ty * 4];
            float4 b0 = *(const float4*)&Bs[kk][tx * 4];
            float4 b1 = *(const float4*)&Bs[kk][64 + tx * 4];
            float av[8] = {a0.x, a0.y, a0.z, a0.w, a1.x, a1.y, a1.z, a1.w};
            float bv[8] = {b0.x, b0.y, b0.z, b0.w, b1.x, b1.y, b1.z, b1.w};
#pragma unroll
            for (int i = 0; i < 8; ++i)
#pragma unroll
                for (int j = 0; j < 8; ++j)
                    acc[i][j] = fmaf(av[i], bv[j], acc[i][j]);
        }
        __syncthreads();
    }
#pragma unroll
    for (int jh = 0; jh < 2; ++jh) {
        int col = n0 + jh * 64 + tx * 4;
#pragma unroll
        for (int ih = 0; ih < 2; ++ih) {
#pragma unroll
            for (int i = 0; i < 4; ++i) {
                int row = m0 + ih * 64 + ty * 4 + i;
                float4 o;
                o.x = acc[ih * 4 + i][jh * 4 + 0];
                o.y = acc[ih * 4 + i][jh * 4 + 1];
                o.z = acc[ih * 4 + i][jh * 4 + 2];
                o.w = acc[ih * 4 + i][jh * 4 + 3];
                *(float4*)(D + (size_t)row * N + col) = o;
            }
        }
    }
}

// ---------------------------------------------------------------------------
// elementwise bf16 helpers
// ---------------------------------------------------------------------------
__global__ __launch_bounds__(256) void cvt_bf16_kernel(
    const float* __restrict__ src, unsigned short* __restrict__ dst, int n)
{
    int i = blockIdx.x * 256 + threadIdx.x;
    if (i < n) dst[i] = bf16_rne(src[i]);
}
__global__ __launch_bounds__(256) void split_bf16_kernel(
    const float* __restrict__ src, unsigned short* __restrict__ hi,
    unsigned short* __restrict__ lo, int n)
{
    int i = blockIdx.x * 256 + threadIdx.x;
    if (i < n) {
        float f = src[i];
        unsigned short h = bf16_rne(f);
        hi[i] = h;
        lo[i] = bf16_rne(f - bf16_tof(h));
    }
}

// ---------------------------------------------------------------------------
// pre-split A for q/k GEMM: a = x * scale(row), split into hi/lo bf16.
// 8 elems / thread; numerics bitwise-identical to in-GEMM conversion.
// ---------------------------------------------------------------------------
__global__ __launch_bounds__(256) void scale_split_kernel(
    const float* __restrict__ x, const float* __restrict__ scale,
    unsigned short* __restrict__ ahi, unsigned short* __restrict__ alo)
{
    size_t i = ((size_t)blockIdx.x * 256 + threadIdx.x) * 8;
    int m = (int)(i >> 10);
    int c = (int)(i & (C_ - 1));
    const float* sr_ = scale + (size_t)(((m >> 12) << 8) + (m & (N_ - 1))) * C_ + c;
    float v[8], s[8];
    *(float4*)(v)     = *(const float4*)(x + i);
    *(float4*)(v + 4) = *(const float4*)(x + i + 4);
    *(float4*)(s)     = *(const float4*)(sr_);
    *(float4*)(s + 4) = *(const float4*)(sr_ + 4);
#pragma unroll
    for (int j = 0; j < 8; ++j) v[j] *= s[j];
    short8 h, l;
    split8(v, h, l);
    *(short8*)(ahi + i) = h;
    *(short8*)(alo + i) = l;
}

// ---------------------------------------------------------------------------
// V transpose: vp_b [bt*256+key][d] (u16) -> vt [bt][d][key] (u16)
// ---------------------------------------------------------------------------
__global__ __launch_bounds__(256) void vtrans_kernel(
    const unsigned short* __restrict__ vpb, unsigned short* __restrict__ vt)
{
    __shared__ unsigned short tile[64][66];   // stride 66 shorts = 33 dwords (odd)
    const int i = blockIdx.x;                 // 128 bt * 4 kblk * 16 dblk
    const int bt = i >> 6;
    const int kb = (i >> 4) & 3;
    const int db = i & 15;
    const int t = threadIdx.x;
    const int r = t >> 2, cs = (t & 3) * 16;
    const size_t base = (size_t)bt * (N_ * C_);
    const unsigned short* src = vpb + base + (size_t)(kb * 64 + r) * C_ + db * 64 + cs;
    *(short8*)&tile[r][cs]     = *(const short8*)src;
    *(short8*)&tile[r][cs + 8] = *(const short8*)(src + 8);
    __syncthreads();
    unsigned short vals[16];
#pragma unroll
    for (int j = 0; j < 16; ++j) vals[j] = tile[cs + j][r];
    unsigned short* dst = vt + base + (size_t)(db * 64 + r) * N_ + kb * 64 + cs;
    *(short8*)dst       = *(const short8*)(vals);
    *(short8*)(dst + 8) = *(const short8*)(vals + 8);
}

// ---------------------------------------------------------------------------
// MFMA GEMM, NT: D[m][n] = sum_k A[m][k]*B[n][k] + bias[n]
// 128x128 tile, BK=32, 256 threads, wave -> 64x64 (4x4 16x16x32 frags).
// MODE 1: A fp32 -> bf16 (RNE), plain B
// MODE 2: A bf16, plain B
// MODE 3: A pre-split bf16 (Ap=hi, Ap2=lo), split B (3 MFMAs, hi-precision)
// OUT 0: f32   OUT 1: bf16   OUT 2: split bf16 (hi->Dp, lo->Dp2)
// LDS rows padded to 36 shorts (18-dword stride: 18*fr mod 32 bijective on
// even banks -> b128 frag reads AND staging writes are bank-uniform).
// ---------------------------------------------------------------------------
template <int MODE, int OUT>
__global__ __launch_bounds__(256) void gemm_mfma(
    const void* __restrict__ Ap, const unsigned short* __restrict__ Ap2,
    const unsigned short* __restrict__ Bhi, const unsigned short* __restrict__ Blo,
    const float* __restrict__ bias, void* __restrict__ Dp, void* __restrict__ Dp2)
{
    constexpr bool SPLIT = (MODE == 3);
    __shared__ unsigned short a_hi[128][36];
    __shared__ unsigned short a_lo[SPLIT ? 128 : 1][36];
    __shared__ unsigned short b_hi[128][36];
    __shared__ unsigned short b_lo[SPLIT ? 128 : 1][36];
    const int t = threadIdx.x;
    const int m0 = blockIdx.x * 128, n0 = blockIdx.y * 128;
    const int sr = t >> 1, sh = (t & 1) * 16;
    const int l = t & 63, w = t >> 6;
    const int moff = (w & 1) * 64, noff = (w >> 1) * 64;
    const int fr = l & 15, quad = l >> 4, fq = quad * 8;
    const int gm = m0 + sr;
    const float* Af = (const float*)Ap;
    const unsigned short* Ab = (const unsigned short*)Ap;

    f32x4 acc[4][4];
#pragma unroll
    for (int i = 0; i < 4; ++i)
#pragma unroll
        for (int j = 0; j < 4; ++j) acc[i][j] = (f32x4){0.f, 0.f, 0.f, 0.f};

    for (int k0 = 0; k0 < C_; k0 += 32) {
        // ---- stage A ----
        if (MODE == 1) {
            const float* g = Af + (size_t)gm * C_ + k0 + sh;
            float v[16];
            *(float4*)(v)      = *(const float4*)(g);
            *(float4*)(v + 4)  = *(const float4*)(g + 4);
            *(float4*)(v + 8)  = *(const float4*)(g + 8);
            *(float4*)(v + 12) = *(const float4*)(g + 12);
            short8 h0, h1;
            cvt8(v, h0);
            cvt8(v + 8, h1);
            *(short8*)&a_hi[sr][sh]     = h0;
            *(short8*)&a_hi[sr][sh + 8] = h1;
        } else {
            const unsigned short* g = Ab + (size_t)gm * C_ + k0 + sh;
            *(short8*)&a_hi[sr][sh]     = *(const short8*)g;
            *(short8*)&a_hi[sr][sh + 8] = *(const short8*)(g + 8);
            if (SPLIT) {
                const unsigned short* g2 = Ap2 + (size_t)gm * C_ + k0 + sh;
                *(short8*)&a_lo[sr][sh]     = *(const short8*)g2;
                *(short8*)&a_lo[sr][sh + 8] = *(const short8*)(g2 + 8);
            }
        }
        // ---- stage B ----
        {
            const unsigned short* g = Bhi + (size_t)(n0 + sr) * C_ + k0 + sh;
            *(short8*)&b_hi[sr][sh]     = *(const short8*)g;
            *(short8*)&b_hi[sr][sh + 8] = *(const short8*)(g + 8);
            if (SPLIT) {
                const unsigned short* g2 = Blo + (size_t)(n0 + sr) * C_ + k0 + sh;
                *(short8*)&b_lo[sr][sh]     = *(const short8*)g2;
                *(short8*)&b_lo[sr][sh + 8] = *(const short8*)(g2 + 8);
            }
        }
        __syncthreads();
        short8 ah[4], al[4];
#pragma unroll
        for (int i = 0; i < 4; ++i) {
            ah[i] = *(const short8*)&a_hi[moff + i * 16 + fr][fq];
            if (SPLIT) al[i] = *(const short8*)&a_lo[moff + i * 16 + fr][fq];
        }
#pragma unroll
        for (int j = 0; j < 4; ++j) {
            short8 bh = *(const short8*)&b_hi[noff + j * 16 + fr][fq];
            short8 bl;
            if (SPLIT) bl = *(const short8*)&b_lo[noff + j * 16 + fr][fq];
#pragma unroll
            for (int i = 0; i < 4; ++i) {
                acc[i][j] = MFMA16(ah[i], bh, acc[i][j]);
                if (SPLIT) {
                    acc[i][j] = MFMA16(ah[i], bl, acc[i][j]);
                    acc[i][j] = MFMA16(al[i], bh, acc[i][j]);
                }
            }
        }
        __syncthreads();
    }
    // ---- epilogue ----
#pragma unroll
    for (int j = 0; j < 4; ++j) {
        int col = n0 + noff + j * 16 + fr;
        float bv = bias ? bias[col] : 0.f;
#pragma unroll
        for (int i = 0; i < 4; ++i) {
#pragma unroll
            for (int r = 0; r < 4; ++r) {
                int row = m0 + moff + i * 16 + quad * 4 + r;
                float val = acc[i][j][r] + bv;
                size_t idx = (size_t)row * C_ + col;
                if (OUT == 0) {
                    ((float*)Dp)[idx] = val;
                } else if (OUT == 1) {
                    ((unsigned short*)Dp)[idx] = bf16_rne(val);
                } else {
                    unsigned short h = bf16_rne(val);
                    ((unsigned short*)Dp)[idx]  = h;
                    ((unsigned short*)Dp2)[idx] = bf16_rne(val - bf16_tof(h));
                }
            }
        }
    }
}

// ---------------------------------------------------------------------------
// MFMA attention: bt = blockIdx.x & 127 so the 8 q-tiles of one bt land on
// one XCD. Q/K pre-split bf16, softmax fp32, PV from pre-transposed V.
// LDS strides: K [68], Vt [132], S [258] -> 2-dword-mod-4 row strides give
// bijective even-bank starts (bank-uniform b128 access). 52.5 KB -> 3 blk/CU.
// ---------------------------------------------------------------------------
__global__ __launch_bounds__(256) void attn_mfma_kernel(
    const unsigned short* __restrict__ qhi, const unsigned short* __restrict__ qlo,
    const unsigned short* __restrict__ khi, const unsigned short* __restrict__ klo,
    const unsigned short* __restrict__ vt, unsigned short* __restrict__ ctxb,
    float* __restrict__ attn_avg)
{
    __shared__ __align__(16) char kv[64 * 68 * 2 * 2];        // 17408 B
    unsigned short (*Khi)[68] = (unsigned short (*)[68])kv;
    unsigned short (*Klo)[68] = (unsigned short (*)[68])(kv + 64 * 68 * 2);
    unsigned short (*Vts)[132] = (unsigned short (*)[132])kv; // 16896 B, union
    __shared__ float S[32][258];                              // 33024 B
    __shared__ float redm[32][8];
    __shared__ float redl[32][8];

    const int bid = blockIdx.x;
    const int bt = bid & 127;
    const int q0 = (bid >> 7) * 32;
    const int t = threadIdx.x;
    const int w = t >> 6, l = t & 63;
    const int qt = (w & 1) * 16;
    const int nt0 = (w >> 1) * 2;
    const int fr = l & 15, quad = l >> 4, fq = quad * 8;
    const int sq = t >> 3, seg = t & 7;
    const size_t base = (size_t)bt * (N_ * C_);
    // staging indices
    const int key_l = t >> 2, cseg = (t & 3) * 16;   // K: 64 rows x 64 cols
    const int vrow = t >> 2, vseg = (t & 3) * 32;    // V: 64 rows x 128 cols
#define KK_(j) (seg * 32 + ((j + seg * 4 + sq) & 31))

    float avg[32];
#pragma unroll
    for (int j = 0; j < 32; ++j) avg[j] = 0.f;

    for (int h = 0; h < H_; ++h) {
        const int hd = h * HD_;
        // ---- Q frags straight from pre-split global ----
        short8 qh[2], ql[2];
        {
            const unsigned short* qrh = qhi + base + (size_t)(q0 + qt + fr) * C_ + hd;
            const unsigned short* qrl = qlo + base + (size_t)(q0 + qt + fr) * C_ + hd;
#pragma unroll
            for (int ks = 0; ks < 2; ++ks) {
                qh[ks] = *(const short8*)(qrh + ks * 32 + fq);
                ql[ks] = *(const short8*)(qrl + ks * 32 + fq);
            }
        }
        // ---- scores: 4 key-chunks of 64 ----
        for (int c = 0; c < 4; ++c) {
            {
                const unsigned short* sh_ = khi + base + (size_t)(c * 64 + key_l) * C_ + hd + cseg;
                const unsigned short* sl_ = klo + base + (size_t)(c * 64 + key_l) * C_ + hd + cseg;
                *(short8*)&Khi[key_l][cseg]     = *(const short8*)sh_;
                *(short8*)&Khi[key_l][cseg + 8] = *(const short8*)(sh_ + 8);
                *(short8*)&Klo[key_l][cseg]     = *(const short8*)sl_;
                *(short8*)&Klo[key_l][cseg + 8] = *(const short8*)(sl_ + 8);
            }
            __syncthreads();
            f32x4 sa[2];
            sa[0] = (f32x4){0.f, 0.f, 0.f, 0.f};
            sa[1] = (f32x4){0.f, 0.f, 0.f, 0.f};
#pragma unroll
            for (int ks = 0; ks < 2; ++ks) {
#pragma unroll
                for (int n = 0; n < 2; ++n) {
                    short8 bh = *(const short8*)&Khi[(nt0 + n) * 16 + fr][ks * 32 + fq];
                    short8 bl = *(const short8*)&Klo[(nt0 + n) * 16 + fr][ks * 32 + fq];
                    sa[n] = MFMA16(qh[ks], bh, sa[n]);
                    sa[n] = MFMA16(qh[ks], bl, sa[n]);
                    sa[n] = MFMA16(ql[ks], bh, sa[n]);
                }
            }
#pragma unroll
            for (int n = 0; n < 2; ++n)
#pragma unroll
                for (int r = 0; r < 4; ++r)
                    S[qt + quad * 4 + r][c * 64 + (nt0 + n) * 16 + fr] = sa[n][r] * 0.125f;
            __syncthreads();
        }
        // ---- softmax over 256 keys (sq+seg rotated access: ~2-way banks) ----
        {
            float m = -3.402823466e38f;
#pragma unroll
            for (int j = 0; j < 32; ++j) m = fmaxf(m, S[sq][KK_(j)]);
            redm[sq][seg] = m;
            __syncthreads();
            float mm = redm[sq][0];
#pragma unroll
            for (int j = 1; j < 8; ++j) mm = fmaxf(mm, redm[sq][j]);
            float e[32];
            float sum = 0.f;
#pragma unroll
            for (int j = 0; j < 32; ++j) {
                e[j] = __expf(S[sq][KK_(j)] - mm);
                sum += e[j];
            }
            redl[sq][seg] = sum;
            __syncthreads();
            float tot = 0.f;
#pragma unroll
            for (int j = 0; j < 8; ++j) tot += redl[sq][j];
            float rl = 1.f / tot;
#pragma unroll
            for (int j = 0; j < 32; ++j) {
                float p = e[j] * rl;
                S[sq][KK_(j)] = p;
                avg[j] += p * (1.f / H_);
            }
            __syncthreads();
        }
        // ---- PV: 2 key-chunks of 128, V pre-transposed in global ----
        f32x4 ca[2];
        ca[0] = (f32x4){0.f, 0.f, 0.f, 0.f};
        ca[1] = (f32x4){0.f, 0.f, 0.f, 0.f};
        for (int c = 0; c < 2; ++c) {
            {
                const unsigned short* src = vt + base + (size_t)(hd + vrow) * N_ + c * 128 + vseg;
#pragma unroll
                for (int j = 0; j < 4; ++j)
                    *(short8*)&Vts[vrow][vseg + j * 8] = *(const short8*)(src + j * 8);
            }
            __syncthreads();
#pragma unroll
            for (int ks = 0; ks < 4; ++ks) {
                const float* pr = &S[qt + fr][c * 128 + ks * 32 + fq];
                float v[8];
                *(float4*)(v)     = *(const float4*)pr;
                *(float4*)(v + 4) = *(const float4*)(pr + 4);
                short8 pa;
                cvt8(v, pa);
#pragma unroll
                for (int n = 0; n < 2; ++n) {
                    short8 vb = *(const short8*)&Vts[(nt0 + n) * 16 + fr][ks * 32 + fq];
                    ca[n] = MFMA16(pa, vb, ca[n]);
                }
            }
            __syncthreads();
        }
        // ---- ctx store (bf16) ----
#pragma unroll
        for (int n = 0; n < 2; ++n)
#pragma unroll
            for (int r = 0; r < 4; ++r)
                ctxb[base + (size_t)(q0 + qt + quad * 4 + r) * C_ + hd + (nt0 + n) * 16 + fr] =
                    bf16_rne(ca[n][r]);
        __syncthreads();
    }
    // ---- attn_avg ----
    {
        float* dst = attn_avg + (size_t)bt * (N_ * N_) + (size_t)(q0 + sq) * N_;
#pragma unroll
        for (int j = 0; j < 32; ++j) dst[KK_(j)] = avg[j];
    }
#undef KK_
}

// ---------------------------------------------------------------------------
// LayerNorm(x + attn_out)
// ---------------------------------------------------------------------------
__global__ __launch_bounds__(256) void ln_kernel(
    const float* __restrict__ x, const float* __restrict__ ao,
    const float* __restrict__ gamma, const float* __restrict__ beta,
    float* __restrict__ out)
{
    __shared__ float r1[256], r2[256];
    int row = blockIdx.x, tid = threadIdx.x;
    const float4 xv = *(const float4*)(x + (size_t)row * C_ + tid * 4);
    const float4 av = *(const float4*)(ao + (size_t)row * C_ + tid * 4);
    float4 h = {xv.x + av.x, xv.y + av.y, xv.z + av.z, xv.w + av.w};
    float s = h.x + h.y + h.z + h.w;
    float s2 = h.x * h.x + h.y * h.y + h.z * h.z + h.w * h.w;
    r1[tid] = s; r2[tid] = s2;
    __syncthreads();
    for (int st = 128; st > 0; st >>= 1) {
        if (tid < st) { r1[tid] += r1[tid + st]; r2[tid] += r2[tid + st]; }
        __syncthreads();
    }
    float mu = r1[0] * (1.f / C_);
    float var = r2[0] * (1.f / C_) - mu * mu;
    float rs = rsqrtf(var + 1e-5f);
    float4 g = *(const float4*)(gamma + tid * 4);
    float4 b = *(const float4*)(beta + tid * 4);
    float4 o = {(h.x - mu) * rs * g.x + b.x,
                (h.y - mu) * rs * g.y + b.y,
                (h.z - mu) * rs * g.z + b.z,
                (h.w - mu) * rs * g.w + b.w};
    *(float4*)(out + (size_t)row * C_ + tid * 4) = o;
}

// ---------------------------------------------------------------------------
extern "C" void kernel_launch(void* const* d_in, const int* in_sizes, int n_in,
                              void* d_out, int out_size, void* d_ws, size_t ws_size,
                              hipStream_t stream)
{
    const float* x     = (const float*)d_in[0];
    const float* y     = (const float*)d_in[1];
    const float* q_e   = (const float*)d_in[3];
    const float* k_e   = (const float*)d_in[4];
    const float* dyn_w = (const float*)d_in[5];
    const float* dyn_b = (const float*)d_in[6];
    const float* v_w   = (const float*)d_in[7];
    const float* v_b   = (const float*)d_in[8];
    const float* in_w  = (const float*)d_in[9];
    const float* in_b  = (const float*)d_in[10];
    const float* out_w = (const float*)d_in[11];
    const float* out_b = (const float*)d_in[12];
    const float* gamma = (const float*)d_in[13];
    const float* beta  = (const float*)d_in[14];

    float* out      = (float*)d_out;
    float* attn_avg = (float*)d_out + (size_t)M_ * C_;

    float* ws = (float*)d_ws;
    size_t o = 0;
    const size_t MC = (size_t)M_ * C_;
    unsigned short* q_hi = (unsigned short*)(ws + o); o += MC / 2;
    unsigned short* q_lo = (unsigned short*)(ws + o); o += MC / 2;
    unsigned short* k_hi = (unsigned short*)(ws + o); o += MC / 2;
    unsigned short* k_lo = (unsigned short*)(ws + o); o += MC / 2;
    unsigned short* qa_hi = (unsigned short*)(ws + o); o += MC / 2;  // also ka_hi, vp_b
    unsigned short* qa_lo = (unsigned short*)(ws + o); o += MC / 2;  // also ka_lo, vt_b
    unsigned short* ctx_b = (unsigned short*)(ws + o); o += MC / 2;
    float* q_scale  = ws + o; o += (size_t)B_ * N_ * C_;
    float* k_scale  = ws + o; o += (size_t)B_ * N_ * C_;
    float* W_comb   = ws + o; o += (size_t)C_ * C_;
    unsigned short* w_hi   = (unsigned short*)(ws + o); o += (size_t)C_ * C_;      // wq+wk hi
    unsigned short* w_lo   = (unsigned short*)(ws + o); o += (size_t)C_ * C_;      // wq+wk lo
    unsigned short* Wc_b   = (unsigned short*)(ws + o); o += (size_t)C_ * C_ / 2;
    unsigned short* ow_b   = (unsigned short*)(ws + o); o += (size_t)C_ * C_ / 2;
    float* qe_sum   = ws + o; o += (size_t)K_ * C_;
    float* ke_sum   = ws + o; o += (size_t)K_ * C_;
    float* dyn      = ws + o; o += (size_t)B_ * N_ * K_;
    float* b_comb   = ws + o; o += C_;
    unsigned short* vp_b = qa_hi;     // dead after k-GEMM
    unsigned short* vt_b = qa_lo;     // dead after k-GEMM
    float* attn_out = (float*)q_hi;   // q_hi+q_lo region (MC floats) dead after attention

    const float* wv = in_w + 2 * C_ * C_;

    expert_sum_kernel<<<dim3(2 * K_ * C_ / 256), 256, 0, stream>>>(q_e, k_e, qe_sum, ke_sum);
    dyn_kernel<<<dim3(B_ * N_), 256, 0, stream>>>(y, dyn_w, dyn_b, dyn);
    scale_kernel<<<dim3(B_ * N_), 256, 0, stream>>>(dyn, qe_sum, ke_sum, q_scale, k_scale);
    bcomb_kernel<<<dim3(C_), 256, 0, stream>>>(wv, v_b, in_b + 2 * C_, b_comb);
    // W_comb = wv @ v_w (fp32, small)
    gemm_f32_nn<<<dim3(C_ / 128, C_ / 128), 256, 0, stream>>>(wv, v_w, W_comb, C_, C_, C_);
    // weight preps
    split_bf16_kernel<<<dim3(2 * C_ * C_ / 256), 256, 0, stream>>>(in_w, w_hi, w_lo, 2 * C_ * C_);
    cvt_bf16_kernel<<<dim3(C_ * C_ / 256), 256, 0, stream>>>(W_comb, Wc_b, C_ * C_);
    cvt_bf16_kernel<<<dim3(C_ * C_ / 256), 256, 0, stream>>>(out_w, ow_b, C_ * C_);
    // qa = split(x * q_scale); q = qa @ wq.T + bq
    scale_split_kernel<<<dim3(M_ * (C_ / 8) / 256), 256, 0, stream>>>(x, q_scale, qa_hi, qa_lo);
    gemm_mfma<3, 2><<<dim3(M_ / 128, C_ / 128), 256, 0, stream>>>(
        qa_hi, qa_lo, w_hi, w_lo, in_b, q_hi, q_lo);
    // ka = split(x * k_scale); k = ka @ wk.T + bk   (reuse qa buffers)
    scale_split_kernel<<<dim3(M_ * (C_ / 8) / 256), 256, 0, stream>>>(x, k_scale, qa_hi, qa_lo);
    gemm_mfma<3, 2><<<dim3(M_ / 128, C_ / 128), 256, 0, stream>>>(
        qa_hi, qa_lo, w_hi + C_ * C_, w_lo + C_ * C_, in_b + C_, k_hi, k_lo);
    // vp = x @ W_comb.T + b_comb  -> bf16  (into qa_hi region)
    gemm_mfma<1, 1><<<dim3(M_ / 128, C_ / 128), 256, 0, stream>>>(
        x, nullptr, Wc_b, nullptr, b_comb, vp_b, nullptr);
    // vt[bt][d][key] = vp transposed (into qa_lo region)
    vtrans_kernel<<<dim3(BT_ * 4 * 16), 256, 0, stream>>>(vp_b, vt_b);
    // attention
    attn_mfma_kernel<<<dim3(BT_ * (N_ / 32)), 256, 0, stream>>>(
        q_hi, q_lo, k_hi, k_lo, vt_b, ctx_b, attn_avg);
    // attn_out = ctx @ out_w.T + out_b   (into q_hi/q_lo region)
    gemm_mfma<2, 0><<<dim3(M_ / 128, C_ / 128), 256, 0, stream>>>(
        ctx_b, nullptr, ow_b, nullptr, out_b, attn_out, nullptr);
    // out = LN(x + attn_out)
    ln_kernel<<<dim3(M_), 256, 0, stream>>>(x, attn_out, gamma, beta, out);

    (void)in_sizes; (void)n_in; (void)out_size; (void)ws_size;
}

// Round 3
// 1873.464 us; speedup vs baseline: 1.2288x; 1.2288x over previous
//
#include <hip/hip_runtime.h>
#include <math.h>

#define B_   8
#define T_   16
#define N_   256
#define C_   1024
#define H_   16
#define HD_  64
#define K_   8
#define BT_  128
#define M_   (BT_*N_)   // 32768 rows

typedef __attribute__((ext_vector_type(8))) short short8;
typedef __attribute__((ext_vector_type(4))) float f32x4;

__device__ __forceinline__ unsigned short bf16_rne(float f) {
    unsigned u = __float_as_uint(f);
    return (unsigned short)((u + 0x7FFFu + ((u >> 16) & 1u)) >> 16);
}
__device__ __forceinline__ float bf16_tof(unsigned short h) {
    return __uint_as_float(((unsigned)h) << 16);
}
__device__ __forceinline__ void split8(const float* v, short8& h, short8& l) {
#pragma unroll
    for (int j = 0; j < 8; ++j) {
        unsigned short hb = bf16_rne(v[j]);
        h[j] = (short)hb;
        l[j] = (short)bf16_rne(v[j] - bf16_tof(hb));
    }
}
__device__ __forceinline__ void cvt8(const float* v, short8& h) {
#pragma unroll
    for (int j = 0; j < 8; ++j) h[j] = (short)bf16_rne(v[j]);
}

#define MFMA16(a, b, c) __builtin_amdgcn_mfma_f32_16x16x32_bf16(a, b, c, 0, 0, 0)

// ---------------------------------------------------------------------------
// expert sum
// ---------------------------------------------------------------------------
__global__ __launch_bounds__(256) void expert_sum_kernel(
    const float* __restrict__ qe, const float* __restrict__ ke,
    float* __restrict__ qsum, float* __restrict__ ksum)
{
    int idx = blockIdx.x * 256 + threadIdx.x;
    int which = idx >> 13;
    int kd = idx & 8191;
    const float* src = (which ? ke : qe) + (size_t)(kd >> 10) * C_ * C_ + (kd & (C_ - 1));
    float s = 0.f;
    for (int i = 0; i < C_; ++i) s += src[(size_t)i * C_];
    (which ? ksum : qsum)[kd] = s;
}

// ---------------------------------------------------------------------------
// dyn = softmax(y @ dyn_w.T + dyn_b)
// ---------------------------------------------------------------------------
__global__ __launch_bounds__(256) void dyn_kernel(
    const float* __restrict__ y, const float* __restrict__ dyn_w,
    const float* __restrict__ dyn_b, float* __restrict__ dyn)
{
    __shared__ float red[256];
    __shared__ float logits[K_];
    int row = blockIdx.x;
    int tid = threadIdx.x;
    const float* yr = y + (size_t)row * C_;
    float part[K_];
#pragma unroll
    for (int k = 0; k < K_; ++k) part[k] = 0.f;
    for (int c = tid; c < C_; c += 256) {
        float yv = yr[c];
#pragma unroll
        for (int k = 0; k < K_; ++k) part[k] += yv * dyn_w[k * C_ + c];
    }
    for (int k = 0; k < K_; ++k) {
        red[tid] = part[k];
        __syncthreads();
        for (int s = 128; s > 0; s >>= 1) {
            if (tid < s) red[tid] += red[tid + s];
            __syncthreads();
        }
        if (tid == 0) logits[k] = red[0] + dyn_b[k];
        __syncthreads();
    }
    if (tid == 0) {
        float m = logits[0];
#pragma unroll
        for (int k = 1; k < K_; ++k) m = fmaxf(m, logits[k]);
        float e[K_];
        float l = 0.f;
#pragma unroll
        for (int k = 0; k < K_; ++k) { e[k] = __expf(logits[k] - m); l += e[k]; }
        float rl = 1.f / l;
#pragma unroll
        for (int k = 0; k < K_; ++k) dyn[(size_t)row * K_ + k] = e[k] * rl;
    }
}

// ---------------------------------------------------------------------------
__global__ __launch_bounds__(256) void scale_kernel(
    const float* __restrict__ dyn, const float* __restrict__ qsum,
    const float* __restrict__ ksum, float* __restrict__ qs, float* __restrict__ ks)
{
    int row = blockIdx.x;
    int d = threadIdx.x * 4;
    float w[K_];
#pragma unroll
    for (int k = 0; k < K_; ++k) w[k] = dyn[(size_t)row * K_ + k];
    float4 aq = {0, 0, 0, 0}, ak = {0, 0, 0, 0};
#pragma unroll
    for (int k = 0; k < K_; ++k) {
        float4 q4 = *(const float4*)(qsum + k * C_ + d);
        float4 k4 = *(const float4*)(ksum + k * C_ + d);
        aq.x += w[k] * q4.x; aq.y += w[k] * q4.y; aq.z += w[k] * q4.z; aq.w += w[k] * q4.w;
        ak.x += w[k] * k4.x; ak.y += w[k] * k4.y; ak.z += w[k] * k4.z; ak.w += w[k] * k4.w;
    }
    *(float4*)(qs + (size_t)row * C_ + d) = aq;
    *(float4*)(ks + (size_t)row * C_ + d) = ak;
}

// ---------------------------------------------------------------------------
__global__ __launch_bounds__(256) void bcomb_kernel(
    const float* __restrict__ wv, const float* __restrict__ v_b,
    const float* __restrict__ bv, float* __restrict__ b_comb)
{
    __shared__ float red[256];
    int j = blockIdx.x, tid = threadIdx.x;
    float p = 0.f;
    for (int e = tid; e < C_; e += 256) p += wv[(size_t)j * C_ + e] * v_b[e];
    red[tid] = p;
    __syncthreads();
    for (int s = 128; s > 0; s >>= 1) {
        if (tid < s) red[tid] += red[tid + s];
        __syncthreads();
    }
    if (tid == 0) b_comb[j] = red[0] + bv[j];
}

// ---------------------------------------------------------------------------
// fp32 NN GEMM (only for 1024^3 W_comb = wv @ v_w)
// ---------------------------------------------------------------------------
__global__ __launch_bounds__(256) void gemm_f32_nn(
    const float* __restrict__ A, const float* __restrict__ Bm,
    float* __restrict__ D, int M, int N, int K)
{
    __shared__ float As[16][132];
    __shared__ float Bs[16][132];
    const int tid = threadIdx.x;
    const int m0 = blockIdx.x * 128;
    const int n0 = blockIdx.y * 128;
    const int tx = tid & 15, ty = tid >> 4;
    const int lr = tid >> 2;
    const int lc = (tid & 3) * 4;
    const int bc = tid >> 4;
    const int bn = (tid & 15) * 8;
    float acc[8][8];
#pragma unroll
    for (int i = 0; i < 8; ++i)
#pragma unroll
        for (int j = 0; j < 8; ++j) acc[i][j] = 0.f;

    for (int k0 = 0; k0 < K; k0 += 16) {
#pragma unroll
        for (int half = 0; half < 2; ++half) {
            int r = lr + half * 64;
            float4 a = *(const float4*)(A + (size_t)(m0 + r) * K + k0 + lc);
            As[lc + 0][r] = a.x; As[lc + 1][r] = a.y;
            As[lc + 2][r] = a.z; As[lc + 3][r] = a.w;
        }
        {
            const float* bp = Bm + (size_t)(k0 + bc) * N + n0 + bn;
            float4 b0 = *(const float4*)(bp);
            float4 b1 = *(const float4*)(bp + 4);
            *(float4*)&Bs[bc][bn] = b0;
            *(float4*)&Bs[bc][bn + 4] = b1;
        }
        __syncthreads();
#pragma unroll
        for (int kk = 0; kk < 16; ++kk) {
            float4 a0 = *(const float4*)&As[kk][ty * 4];
            float4 a1 = *(const float4*)&As[kk][64 + ty * 4];
            float4 b0 = *(const float4*)&Bs[kk][tx * 4];
            float4 b1 = *(const float4*)&Bs[kk][64 + tx * 4];
            float av[8] = {a0.x, a0.y, a0.z, a0.w, a1.x, a1.y, a1.z, a1.w};
            float bv[8] = {b0.x, b0.y, b0.z, b0.w, b1.x, b1.y, b1.z, b1.w};
#pragma unroll
            for (int i = 0; i < 8; ++i)
#pragma unroll
                for (int j = 0; j < 8; ++j)
                    acc[i][j] = fmaf(av[i], bv[j], acc[i][j]);
        }
        __syncthreads();
    }
#pragma unroll
    for (int jh = 0; jh < 2; ++jh) {
        int col = n0 + jh * 64 + tx * 4;
#pragma unroll
        for (int ih = 0; ih < 2; ++ih) {
#pragma unroll
            for (int i = 0; i < 4; ++i) {
                int row = m0 + ih * 64 + ty * 4 + i;
                float4 o;
                o.x = acc[ih * 4 + i][jh * 4 + 0];
                o.y = acc[ih * 4 + i][jh * 4 + 1];
                o.z = acc[ih * 4 + i][jh * 4 + 2];
                o.w = acc[ih * 4 + i][jh * 4 + 3];
                *(float4*)(D + (size_t)row * N + col) = o;
            }
        }
    }
}

// ---------------------------------------------------------------------------
// elementwise bf16 helpers
// ---------------------------------------------------------------------------
__global__ __launch_bounds__(256) void cvt_bf16_kernel(
    const float* __restrict__ src, unsigned short* __restrict__ dst, int n)
{
    int i = blockIdx.x * 256 + threadIdx.x;
    if (i < n) dst[i] = bf16_rne(src[i]);
}
__global__ __launch_bounds__(256) void split_bf16_kernel(
    const float* __restrict__ src, unsigned short* __restrict__ hi,
    unsigned short* __restrict__ lo, int n)
{
    int i = blockIdx.x * 256 + threadIdx.x;
    if (i < n) {
        float f = src[i];
        unsigned short h = bf16_rne(f);
        hi[i] = h;
        lo[i] = bf16_rne(f - bf16_tof(h));
    }
}

// ---------------------------------------------------------------------------
// pre-split A for q/k GEMM: a = x * scale(row), split into hi/lo bf16.
// 8 elems / thread; numerics bitwise-identical to in-GEMM conversion.
// ---------------------------------------------------------------------------
__global__ __launch_bounds__(256) void scale_split_kernel(
    const float* __restrict__ x, const float* __restrict__ scale,
    unsigned short* __restrict__ ahi, unsigned short* __restrict__ alo)
{
    size_t i = ((size_t)blockIdx.x * 256 + threadIdx.x) * 8;
    int m = (int)(i >> 10);
    int c = (int)(i & (C_ - 1));
    const float* sr_ = scale + (size_t)(((m >> 12) << 8) + (m & (N_ - 1))) * C_ + c;
    float v[8], s[8];
    *(float4*)(v)     = *(const float4*)(x + i);
    *(float4*)(v + 4) = *(const float4*)(x + i + 4);
    *(float4*)(s)     = *(const float4*)(sr_);
    *(float4*)(s + 4) = *(const float4*)(sr_ + 4);
#pragma unroll
    for (int j = 0; j < 8; ++j) v[j] *= s[j];
    short8 h, l;
    split8(v, h, l);
    *(short8*)(ahi + i) = h;
    *(short8*)(alo + i) = l;
}

// ---------------------------------------------------------------------------
// V transpose: vp_b [bt*256+key][d] (u16) -> vt [bt][d][key] (u16)
// ---------------------------------------------------------------------------
__global__ __launch_bounds__(256) void vtrans_kernel(
    const unsigned short* __restrict__ vpb, unsigned short* __restrict__ vt)
{
    __shared__ unsigned short tile[64][66];   // stride 66 shorts = 33 dwords (odd)
    const int i = blockIdx.x;                 // 128 bt * 4 kblk * 16 dblk
    const int bt = i >> 6;
    const int kb = (i >> 4) & 3;
    const int db = i & 15;
    const int t = threadIdx.x;
    const int r = t >> 2, cs = (t & 3) * 16;
    const size_t base = (size_t)bt * (N_ * C_);
    const unsigned short* src = vpb + base + (size_t)(kb * 64 + r) * C_ + db * 64 + cs;
    *(short8*)&tile[r][cs]     = *(const short8*)src;
    *(short8*)&tile[r][cs + 8] = *(const short8*)(src + 8);
    __syncthreads();
    unsigned short vals[16];
#pragma unroll
    for (int j = 0; j < 16; ++j) vals[j] = tile[cs + j][r];
    unsigned short* dst = vt + base + (size_t)(db * 64 + r) * N_ + kb * 64 + cs;
    *(short8*)dst       = *(const short8*)(vals);
    *(short8*)(dst + 8) = *(const short8*)(vals + 8);
}

// ---------------------------------------------------------------------------
// MFMA GEMM, NT: D[m][n] = sum_k A[m][k]*B[n][k] + bias[n]
// 128x128 tile, BK=32, 256 threads, wave -> 64x64 (4x4 16x16x32 frags).
// MODE 1: A fp32 -> bf16 (RNE), plain B
// MODE 2: A bf16, plain B
// MODE 3: A pre-split bf16 (Ap=hi, Ap2=lo), split B (3 MFMAs, hi-precision)
// OUT 0: f32   OUT 1: bf16   OUT 2: split bf16 (hi->Dp, lo->Dp2)
// LDS rows padded to 40 shorts = 80 B: 16B-ALIGNED rows (b128 stays b128)
// and 20-dword stride spreads fragment-read start banks across all 32.
// (Round-2 lesson: 36-short rows = 72 B broke 16B alignment -> slow path.)
// ---------------------------------------------------------------------------
template <int MODE, int OUT>
__global__ __launch_bounds__(256) void gemm_mfma(
    const void* __restrict__ Ap, const unsigned short* __restrict__ Ap2,
    const unsigned short* __restrict__ Bhi, const unsigned short* __restrict__ Blo,
    const float* __restrict__ bias, void* __restrict__ Dp, void* __restrict__ Dp2)
{
    constexpr bool SPLIT = (MODE == 3);
    __shared__ unsigned short a_hi[128][40];
    __shared__ unsigned short a_lo[SPLIT ? 128 : 1][40];
    __shared__ unsigned short b_hi[128][40];
    __shared__ unsigned short b_lo[SPLIT ? 128 : 1][40];
    const int t = threadIdx.x;
    const int m0 = blockIdx.x * 128, n0 = blockIdx.y * 128;
    const int sr = t >> 1, sh = (t & 1) * 16;
    const int l = t & 63, w = t >> 6;
    const int moff = (w & 1) * 64, noff = (w >> 1) * 64;
    const int fr = l & 15, quad = l >> 4, fq = quad * 8;
    const int gm = m0 + sr;
    const float* Af = (const float*)Ap;
    const unsigned short* Ab = (const unsigned short*)Ap;

    f32x4 acc[4][4];
#pragma unroll
    for (int i = 0; i < 4; ++i)
#pragma unroll
        for (int j = 0; j < 4; ++j) acc[i][j] = (f32x4){0.f, 0.f, 0.f, 0.f};

    for (int k0 = 0; k0 < C_; k0 += 32) {
        // ---- stage A ----
        if (MODE == 1) {
            const float* g = Af + (size_t)gm * C_ + k0 + sh;
            float v[16];
            *(float4*)(v)      = *(const float4*)(g);
            *(float4*)(v + 4)  = *(const float4*)(g + 4);
            *(float4*)(v + 8)  = *(const float4*)(g + 8);
            *(float4*)(v + 12) = *(const float4*)(g + 12);
            short8 h0, h1;
            cvt8(v, h0);
            cvt8(v + 8, h1);
            *(short8*)&a_hi[sr][sh]     = h0;
            *(short8*)&a_hi[sr][sh + 8] = h1;
        } else {
            const unsigned short* g = Ab + (size_t)gm * C_ + k0 + sh;
            *(short8*)&a_hi[sr][sh]     = *(const short8*)g;
            *(short8*)&a_hi[sr][sh + 8] = *(const short8*)(g + 8);
            if (SPLIT) {
                const unsigned short* g2 = Ap2 + (size_t)gm * C_ + k0 + sh;
                *(short8*)&a_lo[sr][sh]     = *(const short8*)g2;
                *(short8*)&a_lo[sr][sh + 8] = *(const short8*)(g2 + 8);
            }
        }
        // ---- stage B ----
        {
            const unsigned short* g = Bhi + (size_t)(n0 + sr) * C_ + k0 + sh;
            *(short8*)&b_hi[sr][sh]     = *(const short8*)g;
            *(short8*)&b_hi[sr][sh + 8] = *(const short8*)(g + 8);
            if (SPLIT) {
                const unsigned short* g2 = Blo + (size_t)(n0 + sr) * C_ + k0 + sh;
                *(short8*)&b_lo[sr][sh]     = *(const short8*)g2;
                *(short8*)&b_lo[sr][sh + 8] = *(const short8*)(g2 + 8);
            }
        }
        __syncthreads();
        short8 ah[4], al[4];
#pragma unroll
        for (int i = 0; i < 4; ++i) {
            ah[i] = *(const short8*)&a_hi[moff + i * 16 + fr][fq];
            if (SPLIT) al[i] = *(const short8*)&a_lo[moff + i * 16 + fr][fq];
        }
#pragma unroll
        for (int j = 0; j < 4; ++j) {
            short8 bh = *(const short8*)&b_hi[noff + j * 16 + fr][fq];
            short8 bl;
            if (SPLIT) bl = *(const short8*)&b_lo[noff + j * 16 + fr][fq];
#pragma unroll
            for (int i = 0; i < 4; ++i) {
                acc[i][j] = MFMA16(ah[i], bh, acc[i][j]);
                if (SPLIT) {
                    acc[i][j] = MFMA16(ah[i], bl, acc[i][j]);
                    acc[i][j] = MFMA16(al[i], bh, acc[i][j]);
                }
            }
        }
        __syncthreads();
    }
    // ---- epilogue ----
#pragma unroll
    for (int j = 0; j < 4; ++j) {
        int col = n0 + noff + j * 16 + fr;
        float bv = bias ? bias[col] : 0.f;
#pragma unroll
        for (int i = 0; i < 4; ++i) {
#pragma unroll
            for (int r = 0; r < 4; ++r) {
                int row = m0 + moff + i * 16 + quad * 4 + r;
                float val = acc[i][j][r] + bv;
                size_t idx = (size_t)row * C_ + col;
                if (OUT == 0) {
                    ((float*)Dp)[idx] = val;
                } else if (OUT == 1) {
                    ((unsigned short*)Dp)[idx] = bf16_rne(val);
                } else {
                    unsigned short h = bf16_rne(val);
                    ((unsigned short*)Dp)[idx]  = h;
                    ((unsigned short*)Dp2)[idx] = bf16_rne(val - bf16_tof(h));
                }
            }
        }
    }
}

// ---------------------------------------------------------------------------
// MFMA attention: bt = blockIdx.x & 127 so the 8 q-tiles of one bt land on
// one XCD. Q/K pre-split bf16, softmax fp32, PV from pre-transposed V.
// LDS strides (16B-ALIGNED rows, round-1 proven): K [88] (176 B), Vt [136]
// (272 B), S [268] f32 (1072 B). All short8/float4 accesses stay b128.
// ---------------------------------------------------------------------------
__global__ __launch_bounds__(256) void attn_mfma_kernel(
    const unsigned short* __restrict__ qhi, const unsigned short* __restrict__ qlo,
    const unsigned short* __restrict__ khi, const unsigned short* __restrict__ klo,
    const unsigned short* __restrict__ vt, unsigned short* __restrict__ ctxb,
    float* __restrict__ attn_avg)
{
    __shared__ __align__(16) char kv[64 * 88 * 2 * 2];        // 22528 B
    unsigned short (*Khi)[88] = (unsigned short (*)[88])kv;
    unsigned short (*Klo)[88] = (unsigned short (*)[88])(kv + 64 * 88 * 2);
    unsigned short (*Vts)[136] = (unsigned short (*)[136])kv; // 17408 B, union
    __shared__ float S[32][268];                              // 34304 B
    __shared__ float redm[32][8];
    __shared__ float redl[32][8];

    const int bid = blockIdx.x;
    const int bt = bid & 127;
    const int q0 = (bid >> 7) * 32;
    const int t = threadIdx.x;
    const int w = t >> 6, l = t & 63;
    const int qt = (w & 1) * 16;
    const int nt0 = (w >> 1) * 2;
    const int fr = l & 15, quad = l >> 4, fq = quad * 8;
    const int sq = t >> 3, seg = t & 7;
    const size_t base = (size_t)bt * (N_ * C_);
    // staging indices
    const int key_l = t >> 2, cseg = (t & 3) * 16;   // K: 64 rows x 64 cols
    const int vrow = t >> 2, vseg = (t & 3) * 32;    // V: 64 rows x 128 cols

    float avg[32];
#pragma unroll
    for (int j = 0; j < 32; ++j) avg[j] = 0.f;

    for (int h = 0; h < H_; ++h) {
        const int hd = h * HD_;
        // ---- Q frags straight from pre-split global ----
        short8 qh[2], ql[2];
        {
            const unsigned short* qrh = qhi + base + (size_t)(q0 + qt + fr) * C_ + hd;
            const unsigned short* qrl = qlo + base + (size_t)(q0 + qt + fr) * C_ + hd;
#pragma unroll
            for (int ks = 0; ks < 2; ++ks) {
                qh[ks] = *(const short8*)(qrh + ks * 32 + fq);
                ql[ks] = *(const short8*)(qrl + ks * 32 + fq);
            }
        }
        // ---- scores: 4 key-chunks of 64 ----
        for (int c = 0; c < 4; ++c) {
            {
                const unsigned short* sh_ = khi + base + (size_t)(c * 64 + key_l) * C_ + hd + cseg;
                const unsigned short* sl_ = klo + base + (size_t)(c * 64 + key_l) * C_ + hd + cseg;
                *(short8*)&Khi[key_l][cseg]     = *(const short8*)sh_;
                *(short8*)&Khi[key_l][cseg + 8] = *(const short8*)(sh_ + 8);
                *(short8*)&Klo[key_l][cseg]     = *(const short8*)sl_;
                *(short8*)&Klo[key_l][cseg + 8] = *(const short8*)(sl_ + 8);
            }
            __syncthreads();
            f32x4 sa[2];
            sa[0] = (f32x4){0.f, 0.f, 0.f, 0.f};
            sa[1] = (f32x4){0.f, 0.f, 0.f, 0.f};
#pragma unroll
            for (int ks = 0; ks < 2; ++ks) {
#pragma unroll
                for (int n = 0; n < 2; ++n) {
                    short8 bh = *(const short8*)&Khi[(nt0 + n) * 16 + fr][ks * 32 + fq];
                    short8 bl = *(const short8*)&Klo[(nt0 + n) * 16 + fr][ks * 32 + fq];
                    sa[n] = MFMA16(qh[ks], bh, sa[n]);
                    sa[n] = MFMA16(qh[ks], bl, sa[n]);
                    sa[n] = MFMA16(ql[ks], bh, sa[n]);
                }
            }
#pragma unroll
            for (int n = 0; n < 2; ++n)
#pragma unroll
                for (int r = 0; r < 4; ++r)
                    S[qt + quad * 4 + r][c * 64 + (nt0 + n) * 16 + fr] = sa[n][r] * 0.125f;
            __syncthreads();
        }
        // ---- softmax over 256 keys (rotated access to spread banks) ----
        {
            float m = -3.402823466e38f;
#pragma unroll
            for (int j = 0; j < 32; ++j) {
                int kk = seg * 32 + ((j + seg * 4) & 31);
                m = fmaxf(m, S[sq][kk]);
            }
            redm[sq][seg] = m;
            __syncthreads();
            float mm = redm[sq][0];
#pragma unroll
            for (int j = 1; j < 8; ++j) mm = fmaxf(mm, redm[sq][j]);
            float e[32];
            float sum = 0.f;
#pragma unroll
            for (int j = 0; j < 32; ++j) {
                int kk = seg * 32 + ((j + seg * 4) & 31);
                e[j] = __expf(S[sq][kk] - mm);
                sum += e[j];
            }
            redl[sq][seg] = sum;
            __syncthreads();
            float tot = 0.f;
#pragma unroll
            for (int j = 0; j < 8; ++j) tot += redl[sq][j];
            float rl = 1.f / tot;
#pragma unroll
            for (int j = 0; j < 32; ++j) {
                int kk = seg * 32 + ((j + seg * 4) & 31);
                float p = e[j] * rl;
                S[sq][kk] = p;
                avg[j] += p * (1.f / H_);
            }
            __syncthreads();
        }
        // ---- PV: 2 key-chunks of 128, V pre-transposed in global ----
        f32x4 ca[2];
        ca[0] = (f32x4){0.f, 0.f, 0.f, 0.f};
        ca[1] = (f32x4){0.f, 0.f, 0.f, 0.f};
        for (int c = 0; c < 2; ++c) {
            {
                const unsigned short* src = vt + base + (size_t)(hd + vrow) * N_ + c * 128 + vseg;
#pragma unroll
                for (int j = 0; j < 4; ++j)
                    *(short8*)&Vts[vrow][vseg + j * 8] = *(const short8*)(src + j * 8);
            }
            __syncthreads();
#pragma unroll
            for (int ks = 0; ks < 4; ++ks) {
                const float* pr = &S[qt + fr][c * 128 + ks * 32 + fq];
                float v[8];
                *(float4*)(v)     = *(const float4*)pr;
                *(float4*)(v + 4) = *(const float4*)(pr + 4);
                short8 pa;
                cvt8(v, pa);
#pragma unroll
                for (int n = 0; n < 2; ++n) {
                    short8 vb = *(const short8*)&Vts[(nt0 + n) * 16 + fr][ks * 32 + fq];
                    ca[n] = MFMA16(pa, vb, ca[n]);
                }
            }
            __syncthreads();
        }
        // ---- ctx store (bf16) ----
#pragma unroll
        for (int n = 0; n < 2; ++n)
#pragma unroll
            for (int r = 0; r < 4; ++r)
                ctxb[base + (size_t)(q0 + qt + quad * 4 + r) * C_ + hd + (nt0 + n) * 16 + fr] =
                    bf16_rne(ca[n][r]);
        __syncthreads();
    }
    // ---- attn_avg ----
    {
        float* dst = attn_avg + (size_t)bt * (N_ * N_) + (size_t)(q0 + sq) * N_;
#pragma unroll
        for (int j = 0; j < 32; ++j) {
            int kk = seg * 32 + ((j + seg * 4) & 31);
            dst[kk] = avg[j];
        }
    }
}

// ---------------------------------------------------------------------------
// LayerNorm(x + attn_out)
// ---------------------------------------------------------------------------
__global__ __launch_bounds__(256) void ln_kernel(
    const float* __restrict__ x, const float* __restrict__ ao,
    const float* __restrict__ gamma, const float* __restrict__ beta,
    float* __restrict__ out)
{
    __shared__ float r1[256], r2[256];
    int row = blockIdx.x, tid = threadIdx.x;
    const float4 xv = *(const float4*)(x + (size_t)row * C_ + tid * 4);
    const float4 av = *(const float4*)(ao + (size_t)row * C_ + tid * 4);
    float4 h = {xv.x + av.x, xv.y + av.y, xv.z + av.z, xv.w + av.w};
    float s = h.x + h.y + h.z + h.w;
    float s2 = h.x * h.x + h.y * h.y + h.z * h.z + h.w * h.w;
    r1[tid] = s; r2[tid] = s2;
    __syncthreads();
    for (int st = 128; st > 0; st >>= 1) {
        if (tid < st) { r1[tid] += r1[tid + st]; r2[tid] += r2[tid + st]; }
        __syncthreads();
    }
    float mu = r1[0] * (1.f / C_);
    float var = r2[0] * (1.f / C_) - mu * mu;
    float rs = rsqrtf(var + 1e-5f);
    float4 g = *(const float4*)(gamma + tid * 4);
    float4 b = *(const float4*)(beta + tid * 4);
    float4 o = {(h.x - mu) * rs * g.x + b.x,
                (h.y - mu) * rs * g.y + b.y,
                (h.z - mu) * rs * g.z + b.z,
                (h.w - mu) * rs * g.w + b.w};
    *(float4*)(out + (size_t)row * C_ + tid * 4) = o;
}

// ---------------------------------------------------------------------------
extern "C" void kernel_launch(void* const* d_in, const int* in_sizes, int n_in,
                              void* d_out, int out_size, void* d_ws, size_t ws_size,
                              hipStream_t stream)
{
    const float* x     = (const float*)d_in[0];
    const float* y     = (const float*)d_in[1];
    const float* q_e   = (const float*)d_in[3];
    const float* k_e   = (const float*)d_in[4];
    const float* dyn_w = (const float*)d_in[5];
    const float* dyn_b = (const float*)d_in[6];
    const float* v_w   = (const float*)d_in[7];
    const float* v_b   = (const float*)d_in[8];
    const float* in_w  = (const float*)d_in[9];
    const float* in_b  = (const float*)d_in[10];
    const float* out_w = (const float*)d_in[11];
    const float* out_b = (const float*)d_in[12];
    const float* gamma = (const float*)d_in[13];
    const float* beta  = (const float*)d_in[14];

    float* out      = (float*)d_out;
    float* attn_avg = (float*)d_out + (size_t)M_ * C_;

    float* ws = (float*)d_ws;
    size_t o = 0;
    const size_t MC = (size_t)M_ * C_;
    unsigned short* q_hi = (unsigned short*)(ws + o); o += MC / 2;
    unsigned short* q_lo = (unsigned short*)(ws + o); o += MC / 2;
    unsigned short* k_hi = (unsigned short*)(ws + o); o += MC / 2;
    unsigned short* k_lo = (unsigned short*)(ws + o); o += MC / 2;
    unsigned short* qa_hi = (unsigned short*)(ws + o); o += MC / 2;  // also ka_hi, vp_b
    unsigned short* qa_lo = (unsigned short*)(ws + o); o += MC / 2;  // also ka_lo, vt_b
    unsigned short* ctx_b = (unsigned short*)(ws + o); o += MC / 2;
    float* q_scale  = ws + o; o += (size_t)B_ * N_ * C_;
    float* k_scale  = ws + o; o += (size_t)B_ * N_ * C_;
    float* W_comb   = ws + o; o += (size_t)C_ * C_;
    unsigned short* w_hi   = (unsigned short*)(ws + o); o += (size_t)C_ * C_;      // wq+wk hi
    unsigned short* w_lo   = (unsigned short*)(ws + o); o += (size_t)C_ * C_;      // wq+wk lo
    unsigned short* Wc_b   = (unsigned short*)(ws + o); o += (size_t)C_ * C_ / 2;
    unsigned short* ow_b   = (unsigned short*)(ws + o); o += (size_t)C_ * C_ / 2;
    float* qe_sum   = ws + o; o += (size_t)K_ * C_;
    float* ke_sum   = ws + o; o += (size_t)K_ * C_;
    float* dyn      = ws + o; o += (size_t)B_ * N_ * K_;
    float* b_comb   = ws + o; o += C_;
    unsigned short* vp_b = qa_hi;     // dead after k-GEMM
    unsigned short* vt_b = qa_lo;     // dead after k-GEMM
    float* attn_out = (float*)q_hi;   // q_hi+q_lo region (MC floats) dead after attention

    const float* wv = in_w + 2 * C_ * C_;

    expert_sum_kernel<<<dim3(2 * K_ * C_ / 256), 256, 0, stream>>>(q_e, k_e, qe_sum, ke_sum);
    dyn_kernel<<<dim3(B_ * N_), 256, 0, stream>>>(y, dyn_w, dyn_b, dyn);
    scale_kernel<<<dim3(B_ * N_), 256, 0, stream>>>(dyn, qe_sum, ke_sum, q_scale, k_scale);
    bcomb_kernel<<<dim3(C_), 256, 0, stream>>>(wv, v_b, in_b + 2 * C_, b_comb);
    // W_comb = wv @ v_w (fp32, small)
    gemm_f32_nn<<<dim3(C_ / 128, C_ / 128), 256, 0, stream>>>(wv, v_w, W_comb, C_, C_, C_);
    // weight preps
    split_bf16_kernel<<<dim3(2 * C_ * C_ / 256), 256, 0, stream>>>(in_w, w_hi, w_lo, 2 * C_ * C_);
    cvt_bf16_kernel<<<dim3(C_ * C_ / 256), 256, 0, stream>>>(W_comb, Wc_b, C_ * C_);
    cvt_bf16_kernel<<<dim3(C_ * C_ / 256), 256, 0, stream>>>(out_w, ow_b, C_ * C_);
    // qa = split(x * q_scale); q = qa @ wq.T + bq
    scale_split_kernel<<<dim3(M_ * (C_ / 8) / 256), 256, 0, stream>>>(x, q_scale, qa_hi, qa_lo);
    gemm_mfma<3, 2><<<dim3(M_ / 128, C_ / 128), 256, 0, stream>>>(
        qa_hi, qa_lo, w_hi, w_lo, in_b, q_hi, q_lo);
    // ka = split(x * k_scale); k = ka @ wk.T + bk   (reuse qa buffers)
    scale_split_kernel<<<dim3(M_ * (C_ / 8) / 256), 256, 0, stream>>>(x, k_scale, qa_hi, qa_lo);
    gemm_mfma<3, 2><<<dim3(M_ / 128, C_ / 128), 256, 0, stream>>>(
        qa_hi, qa_lo, w_hi + C_ * C_, w_lo + C_ * C_, in_b + C_, k_hi, k_lo);
    // vp = x @ W_comb.T + b_comb  -> bf16  (into qa_hi region)
    gemm_mfma<1, 1><<<dim3(M_ / 128, C_ / 128), 256, 0, stream>>>(
        x, nullptr, Wc_b, nullptr, b_comb, vp_b, nullptr);
    // vt[bt][d][key] = vp transposed (into qa_lo region)
    vtrans_kernel<<<dim3(BT_ * 4 * 16), 256, 0, stream>>>(vp_b, vt_b);
    // attention
    attn_mfma_kernel<<<dim3(BT_ * (N_ / 32)), 256, 0, stream>>>(
        q_hi, q_lo, k_hi, k_lo, vt_b, ctx_b, attn_avg);
    // attn_out = ctx @ out_w.T + out_b   (into q_hi/q_lo region)
    gemm_mfma<2, 0><<<dim3(M_ / 128, C_ / 128), 256, 0, stream>>>(
        ctx_b, nullptr, ow_b, nullptr, out_b, attn_out, nullptr);
    // out = LN(x + attn_out)
    ln_kernel<<<dim3(M_), 256, 0, stream>>>(x, attn_out, gamma, beta, out);

    (void)in_sizes; (void)n_in; (void)out_size; (void)ws_size;
}

// Round 4
// 1774.875 us; speedup vs baseline: 1.2971x; 1.0555x over previous
//
#include <hip/hip_runtime.h>
#include <math.h>

#define B_   8
#define T_   16
#define N_   256
#define C_   1024
#define H_   16
#define HD_  64
#define K_   8
#define BT_  128
#define M_   (BT_*N_)   // 32768 rows

typedef __attribute__((ext_vector_type(8))) short short8;
typedef __attribute__((ext_vector_type(4))) float f32x4;

__device__ __forceinline__ unsigned short bf16_rne(float f) {
    unsigned u = __float_as_uint(f);
    return (unsigned short)((u + 0x7FFFu + ((u >> 16) & 1u)) >> 16);
}
__device__ __forceinline__ float bf16_tof(unsigned short h) {
    return __uint_as_float(((unsigned)h) << 16);
}
__device__ __forceinline__ void split8(const float* v, short8& h, short8& l) {
#pragma unroll
    for (int j = 0; j < 8; ++j) {
        unsigned short hb = bf16_rne(v[j]);
        h[j] = (short)hb;
        l[j] = (short)bf16_rne(v[j] - bf16_tof(hb));
    }
}
__device__ __forceinline__ void cvt8(const float* v, short8& h) {
#pragma unroll
    for (int j = 0; j < 8; ++j) h[j] = (short)bf16_rne(v[j]);
}

#define MFMA16(a, b, c) __builtin_amdgcn_mfma_f32_16x16x32_bf16(a, b, c, 0, 0, 0)

// async global->LDS, 16B per lane; LDS dest = wave-uniform base + lane*16
#define GLD16(gp, lp) __builtin_amdgcn_global_load_lds( \
    (const __attribute__((address_space(1))) unsigned int*)(gp), \
    (__attribute__((address_space(3))) unsigned int*)(lp), 16, 0, 0)

// ---------------------------------------------------------------------------
// expert sum
// ---------------------------------------------------------------------------
__global__ __launch_bounds__(256) void expert_sum_kernel(
    const float* __restrict__ qe, const float* __restrict__ ke,
    float* __restrict__ qsum, float* __restrict__ ksum)
{
    int idx = blockIdx.x * 256 + threadIdx.x;
    int which = idx >> 13;
    int kd = idx & 8191;
    const float* src = (which ? ke : qe) + (size_t)(kd >> 10) * C_ * C_ + (kd & (C_ - 1));
    float s = 0.f;
    for (int i = 0; i < C_; ++i) s += src[(size_t)i * C_];
    (which ? ksum : qsum)[kd] = s;
}

// ---------------------------------------------------------------------------
// dyn = softmax(y @ dyn_w.T + dyn_b)
// ---------------------------------------------------------------------------
__global__ __launch_bounds__(256) void dyn_kernel(
    const float* __restrict__ y, const float* __restrict__ dyn_w,
    const float* __restrict__ dyn_b, float* __restrict__ dyn)
{
    __shared__ float red[256];
    __shared__ float logits[K_];
    int row = blockIdx.x;
    int tid = threadIdx.x;
    const float* yr = y + (size_t)row * C_;
    float part[K_];
#pragma unroll
    for (int k = 0; k < K_; ++k) part[k] = 0.f;
    for (int c = tid; c < C_; c += 256) {
        float yv = yr[c];
#pragma unroll
        for (int k = 0; k < K_; ++k) part[k] += yv * dyn_w[k * C_ + c];
    }
    for (int k = 0; k < K_; ++k) {
        red[tid] = part[k];
        __syncthreads();
        for (int s = 128; s > 0; s >>= 1) {
            if (tid < s) red[tid] += red[tid + s];
            __syncthreads();
        }
        if (tid == 0) logits[k] = red[0] + dyn_b[k];
        __syncthreads();
    }
    if (tid == 0) {
        float m = logits[0];
#pragma unroll
        for (int k = 1; k < K_; ++k) m = fmaxf(m, logits[k]);
        float e[K_];
        float l = 0.f;
#pragma unroll
        for (int k = 0; k < K_; ++k) { e[k] = __expf(logits[k] - m); l += e[k]; }
        float rl = 1.f / l;
#pragma unroll
        for (int k = 0; k < K_; ++k) dyn[(size_t)row * K_ + k] = e[k] * rl;
    }
}

// ---------------------------------------------------------------------------
__global__ __launch_bounds__(256) void scale_kernel(
    const float* __restrict__ dyn, const float* __restrict__ qsum,
    const float* __restrict__ ksum, float* __restrict__ qs, float* __restrict__ ks)
{
    int row = blockIdx.x;
    int d = threadIdx.x * 4;
    float w[K_];
#pragma unroll
    for (int k = 0; k < K_; ++k) w[k] = dyn[(size_t)row * K_ + k];
    float4 aq = {0, 0, 0, 0}, ak = {0, 0, 0, 0};
#pragma unroll
    for (int k = 0; k < K_; ++k) {
        float4 q4 = *(const float4*)(qsum + k * C_ + d);
        float4 k4 = *(const float4*)(ksum + k * C_ + d);
        aq.x += w[k] * q4.x; aq.y += w[k] * q4.y; aq.z += w[k] * q4.z; aq.w += w[k] * q4.w;
        ak.x += w[k] * k4.x; ak.y += w[k] * k4.y; ak.z += w[k] * k4.z; ak.w += w[k] * k4.w;
    }
    *(float4*)(qs + (size_t)row * C_ + d) = aq;
    *(float4*)(ks + (size_t)row * C_ + d) = ak;
}

// ---------------------------------------------------------------------------
__global__ __launch_bounds__(256) void bcomb_kernel(
    const float* __restrict__ wv, const float* __restrict__ v_b,
    const float* __restrict__ bv, float* __restrict__ b_comb)
{
    __shared__ float red[256];
    int j = blockIdx.x, tid = threadIdx.x;
    float p = 0.f;
    for (int e = tid; e < C_; e += 256) p += wv[(size_t)j * C_ + e] * v_b[e];
    red[tid] = p;
    __syncthreads();
    for (int s = 128; s > 0; s >>= 1) {
        if (tid < s) red[tid] += red[tid + s];
        __syncthreads();
    }
    if (tid == 0) b_comb[j] = red[0] + bv[j];
}

// ---------------------------------------------------------------------------
// fp32 NN GEMM (only for 1024^3 W_comb = wv @ v_w)
// ---------------------------------------------------------------------------
__global__ __launch_bounds__(256) void gemm_f32_nn(
    const float* __restrict__ A, const float* __restrict__ Bm,
    float* __restrict__ D, int M, int N, int K)
{
    __shared__ float As[16][132];
    __shared__ float Bs[16][132];
    const int tid = threadIdx.x;
    const int m0 = blockIdx.x * 128;
    const int n0 = blockIdx.y * 128;
    const int tx = tid & 15, ty = tid >> 4;
    const int lr = tid >> 2;
    const int lc = (tid & 3) * 4;
    const int bc = tid >> 4;
    const int bn = (tid & 15) * 8;
    float acc[8][8];
#pragma unroll
    for (int i = 0; i < 8; ++i)
#pragma unroll
        for (int j = 0; j < 8; ++j) acc[i][j] = 0.f;

    for (int k0 = 0; k0 < K; k0 += 16) {
#pragma unroll
        for (int half = 0; half < 2; ++half) {
            int r = lr + half * 64;
            float4 a = *(const float4*)(A + (size_t)(m0 + r) * K + k0 + lc);
            As[lc + 0][r] = a.x; As[lc + 1][r] = a.y;
            As[lc + 2][r] = a.z; As[lc + 3][r] = a.w;
        }
        {
            const float* bp = Bm + (size_t)(k0 + bc) * N + n0 + bn;
            float4 b0 = *(const float4*)(bp);
            float4 b1 = *(const float4*)(bp + 4);
            *(float4*)&Bs[bc][bn] = b0;
            *(float4*)&Bs[bc][bn + 4] = b1;
        }
        __syncthreads();
#pragma unroll
        for (int kk = 0; kk < 16; ++kk) {
            float4 a0 = *(const float4*)&As[kk][ty * 4];
            float4 a1 = *(const float4*)&As[kk][64 + ty * 4];
            float4 b0 = *(const float4*)&Bs[kk][tx * 4];
            float4 b1 = *(const float4*)&Bs[kk][64 + tx * 4];
            float av[8] = {a0.x, a0.y, a0.z, a0.w, a1.x, a1.y, a1.z, a1.w};
            float bv[8] = {b0.x, b0.y, b0.z, b0.w, b1.x, b1.y, b1.z, b1.w};
#pragma unroll
            for (int i = 0; i < 8; ++i)
#pragma unroll
                for (int j = 0; j < 8; ++j)
                    acc[i][j] = fmaf(av[i], bv[j], acc[i][j]);
        }
        __syncthreads();
    }
#pragma unroll
    for (int jh = 0; jh < 2; ++jh) {
        int col = n0 + jh * 64 + tx * 4;
#pragma unroll
        for (int ih = 0; ih < 2; ++ih) {
#pragma unroll
            for (int i = 0; i < 4; ++i) {
                int row = m0 + ih * 64 + ty * 4 + i;
                float4 o;
                o.x = acc[ih * 4 + i][jh * 4 + 0];
                o.y = acc[ih * 4 + i][jh * 4 + 1];
                o.z = acc[ih * 4 + i][jh * 4 + 2];
                o.w = acc[ih * 4 + i][jh * 4 + 3];
                *(float4*)(D + (size_t)row * N + col) = o;
            }
        }
    }
}

// ---------------------------------------------------------------------------
// elementwise bf16 helpers
// ---------------------------------------------------------------------------
__global__ __launch_bounds__(256) void cvt_bf16_kernel(
    const float* __restrict__ src, unsigned short* __restrict__ dst, int n)
{
    int i = blockIdx.x * 256 + threadIdx.x;
    if (i < n) dst[i] = bf16_rne(src[i]);
}
__global__ __launch_bounds__(256) void split_bf16_kernel(
    const float* __restrict__ src, unsigned short* __restrict__ hi,
    unsigned short* __restrict__ lo, int n)
{
    int i = blockIdx.x * 256 + threadIdx.x;
    if (i < n) {
        float f = src[i];
        unsigned short h = bf16_rne(f);
        hi[i] = h;
        lo[i] = bf16_rne(f - bf16_tof(h));
    }
}
// vectorized fp32 -> bf16, 8 elems/thread
__global__ __launch_bounds__(256) void cvt8_bf16_kernel(
    const float* __restrict__ src, unsigned short* __restrict__ dst)
{
    size_t i = ((size_t)blockIdx.x * 256 + threadIdx.x) * 8;
    float v[8];
    *(float4*)(v)     = *(const float4*)(src + i);
    *(float4*)(v + 4) = *(const float4*)(src + i + 4);
    short8 h;
    cvt8(v, h);
    *(short8*)(dst + i) = h;
}

// ---------------------------------------------------------------------------
// pre-split A for q/k GEMM: a = x * scale(row), split into hi/lo bf16.
// ---------------------------------------------------------------------------
__global__ __launch_bounds__(256) void scale_split_kernel(
    const float* __restrict__ x, const float* __restrict__ scale,
    unsigned short* __restrict__ ahi, unsigned short* __restrict__ alo)
{
    size_t i = ((size_t)blockIdx.x * 256 + threadIdx.x) * 8;
    int m = (int)(i >> 10);
    int c = (int)(i & (C_ - 1));
    const float* sr_ = scale + (size_t)(((m >> 12) << 8) + (m & (N_ - 1))) * C_ + c;
    float v[8], s[8];
    *(float4*)(v)     = *(const float4*)(x + i);
    *(float4*)(v + 4) = *(const float4*)(x + i + 4);
    *(float4*)(s)     = *(const float4*)(sr_);
    *(float4*)(s + 4) = *(const float4*)(sr_ + 4);
#pragma unroll
    for (int j = 0; j < 8; ++j) v[j] *= s[j];
    short8 h, l;
    split8(v, h, l);
    *(short8*)(ahi + i) = h;
    *(short8*)(alo + i) = l;
}

// ---------------------------------------------------------------------------
// V transpose: vp_b [bt*256+key][d] (u16) -> vt [bt][d][key] (u16)
// ---------------------------------------------------------------------------
__global__ __launch_bounds__(256) void vtrans_kernel(
    const unsigned short* __restrict__ vpb, unsigned short* __restrict__ vt)
{
    __shared__ unsigned short tile[64][66];   // stride 66 shorts = 33 dwords (odd)
    const int i = blockIdx.x;                 // 128 bt * 4 kblk * 16 dblk
    const int bt = i >> 6;
    const int kb = (i >> 4) & 3;
    const int db = i & 15;
    const int t = threadIdx.x;
    const int r = t >> 2, cs = (t & 3) * 16;
    const size_t base = (size_t)bt * (N_ * C_);
    const unsigned short* src = vpb + base + (size_t)(kb * 64 + r) * C_ + db * 64 + cs;
    *(short8*)&tile[r][cs]     = *(const short8*)src;
    *(short8*)&tile[r][cs + 8] = *(const short8*)(src + 8);
    __syncthreads();
    unsigned short vals[16];
#pragma unroll
    for (int j = 0; j < 16; ++j) vals[j] = tile[cs + j][r];
    unsigned short* dst = vt + base + (size_t)(db * 64 + r) * N_ + kb * 64 + cs;
    *(short8*)dst       = *(const short8*)(vals);
    *(short8*)(dst + 8) = *(const short8*)(vals + 8);
}

// ---------------------------------------------------------------------------
// MFMA GEMM, NT: D[m][n] = sum_k A[m][k]*B[n][k] + bias[n]
// 128x128 tile, BK=32, 256 threads, wave -> 64x64 (4x4 16x16x32 frags).
// MODE 2: plain bf16 A,B.  MODE 3: split bf16 A(hi/lo) x B(hi/lo), 3 MFMAs.
// OUT 0: f32   OUT 1: bf16   OUT 2: split bf16 (hi->Dp, lo->Dp2)
// Staging via global_load_lds width=16 into LINEAR [128][32] tiles (64 B
// rows). Frag reads (16*fr + 4*quad) mod 32 spread 8 lanes over each of 8
// 16B slots -> bank-balanced without padding; gload_lds needs linear dest.
// Grid is (n-fast, m-slow): the 8 n-blocks sharing an A panel dispatch
// adjacently -> A panel served from L3 instead of 8x HBM re-reads.
// ---------------------------------------------------------------------------
template <int MODE, int OUT>
__global__ __launch_bounds__(256) void gemm_mfma(
    const unsigned short* __restrict__ Ahi, const unsigned short* __restrict__ Alo,
    const unsigned short* __restrict__ Bhi, const unsigned short* __restrict__ Blo,
    const float* __restrict__ bias, void* __restrict__ Dp, void* __restrict__ Dp2)
{
    constexpr bool SPLIT = (MODE == 3);
    __shared__ __align__(16) unsigned short a_hi[128][32];
    __shared__ __align__(16) unsigned short b_hi[128][32];
    __shared__ __align__(16) unsigned short a_lo[SPLIT ? 128 : 1][32];
    __shared__ __align__(16) unsigned short b_lo[SPLIT ? 128 : 1][32];
    const int t = threadIdx.x;
    const int n0 = blockIdx.x * 128, m0 = blockIdx.y * 128;
    const int l = t & 63, w = t >> 6;
    const int moff = (w & 1) * 64, noff = (w >> 1) * 64;
    const int fr = l & 15, quad = l >> 4, fq = quad * 8;
    const int grow = t >> 2;        // 0..63: row within 64-row half
    const int gch = (t & 3) * 8;    // 16B chunk within 64B row
    const int wb = w * 1024;        // this wave's 1KB slice of a 4KB half

    f32x4 acc[4][4];
#pragma unroll
    for (int i = 0; i < 4; ++i)
#pragma unroll
        for (int j = 0; j < 4; ++j) acc[i][j] = (f32x4){0.f, 0.f, 0.f, 0.f};

    for (int k0 = 0; k0 < C_; k0 += 32) {
        {
            const size_t ga0 = (size_t)(m0 + grow) * C_ + k0 + gch;
            const size_t ga1 = (size_t)(m0 + 64 + grow) * C_ + k0 + gch;
            const size_t gb0 = (size_t)(n0 + grow) * C_ + k0 + gch;
            const size_t gb1 = (size_t)(n0 + 64 + grow) * C_ + k0 + gch;
            GLD16(Ahi + ga0, (char*)&a_hi[0][0] + wb);
            GLD16(Ahi + ga1, (char*)&a_hi[0][0] + 4096 + wb);
            GLD16(Bhi + gb0, (char*)&b_hi[0][0] + wb);
            GLD16(Bhi + gb1, (char*)&b_hi[0][0] + 4096 + wb);
            if (SPLIT) {
                GLD16(Alo + ga0, (char*)&a_lo[0][0] + wb);
                GLD16(Alo + ga1, (char*)&a_lo[0][0] + 4096 + wb);
                GLD16(Blo + gb0, (char*)&b_lo[0][0] + wb);
                GLD16(Blo + gb1, (char*)&b_lo[0][0] + 4096 + wb);
            }
        }
        __syncthreads();
        short8 ah[4], al[4];
#pragma unroll
        for (int i = 0; i < 4; ++i) {
            ah[i] = *(const short8*)&a_hi[moff + i * 16 + fr][fq];
            if (SPLIT) al[i] = *(const short8*)&a_lo[moff + i * 16 + fr][fq];
        }
#pragma unroll
        for (int j = 0; j < 4; ++j) {
            short8 bh = *(const short8*)&b_hi[noff + j * 16 + fr][fq];
            short8 bl;
            if (SPLIT) bl = *(const short8*)&b_lo[noff + j * 16 + fr][fq];
#pragma unroll
            for (int i = 0; i < 4; ++i) {
                acc[i][j] = MFMA16(ah[i], bh, acc[i][j]);
                if (SPLIT) {
                    acc[i][j] = MFMA16(ah[i], bl, acc[i][j]);
                    acc[i][j] = MFMA16(al[i], bh, acc[i][j]);
                }
            }
        }
        __syncthreads();
    }
    // ---- epilogue ----
#pragma unroll
    for (int j = 0; j < 4; ++j) {
        int col = n0 + noff + j * 16 + fr;
        float bv = bias ? bias[col] : 0.f;
#pragma unroll
        for (int i = 0; i < 4; ++i) {
#pragma unroll
            for (int r = 0; r < 4; ++r) {
                int row = m0 + moff + i * 16 + quad * 4 + r;
                float val = acc[i][j][r] + bv;
                size_t idx = (size_t)row * C_ + col;
                if (OUT == 0) {
                    ((float*)Dp)[idx] = val;
                } else if (OUT == 1) {
                    ((unsigned short*)Dp)[idx] = bf16_rne(val);
                } else {
                    unsigned short h = bf16_rne(val);
                    ((unsigned short*)Dp)[idx]  = h;
                    ((unsigned short*)Dp2)[idx] = bf16_rne(val - bf16_tof(h));
                }
            }
        }
    }
}

// ---------------------------------------------------------------------------
// MFMA attention: bt = blockIdx.x & 127 so the 8 q-tiles of one bt land on
// one XCD. Q/K pre-split bf16, softmax fp32, PV from pre-transposed V.
// LDS strides 16B-aligned: K [88] (176 B), Vt [136] (272 B), S [268] f32.
// Softmax walk rotated by (seg*4 + sq): bank = 13*ls + 4*seg (odd multiplier)
// -> 2-way max on the scalar passes (round-2's rotation, round-1's strides).
// ---------------------------------------------------------------------------
__global__ __launch_bounds__(256) void attn_mfma_kernel(
    const unsigned short* __restrict__ qhi, const unsigned short* __restrict__ qlo,
    const unsigned short* __restrict__ khi, const unsigned short* __restrict__ klo,
    const unsigned short* __restrict__ vt, unsigned short* __restrict__ ctxb,
    float* __restrict__ attn_avg)
{
    __shared__ __align__(16) char kv[64 * 88 * 2 * 2];        // 22528 B
    unsigned short (*Khi)[88] = (unsigned short (*)[88])kv;
    unsigned short (*Klo)[88] = (unsigned short (*)[88])(kv + 64 * 88 * 2);
    unsigned short (*Vts)[136] = (unsigned short (*)[136])kv; // 17408 B, union
    __shared__ float S[32][268];                              // 34304 B
    __shared__ float redm[32][8];
    __shared__ float redl[32][8];

    const int bid = blockIdx.x;
    const int bt = bid & 127;
    const int q0 = (bid >> 7) * 32;
    const int t = threadIdx.x;
    const int w = t >> 6, l = t & 63;
    const int qt = (w & 1) * 16;
    const int nt0 = (w >> 1) * 2;
    const int fr = l & 15, quad = l >> 4, fq = quad * 8;
    const int sq = t >> 3, seg = t & 7;
    const size_t base = (size_t)bt * (N_ * C_);
    const int key_l = t >> 2, cseg = (t & 3) * 16;   // K: 64 rows x 64 cols
    const int vrow = t >> 2, vseg = (t & 3) * 32;    // V: 64 rows x 128 cols
#define KK_(j) (seg * 32 + ((j + seg * 4 + sq) & 31))

    float avg[32];
#pragma unroll
    for (int j = 0; j < 32; ++j) avg[j] = 0.f;

    for (int h = 0; h < H_; ++h) {
        const int hd = h * HD_;
        // ---- Q frags straight from pre-split global ----
        short8 qh[2], ql[2];
        {
            const unsigned short* qrh = qhi + base + (size_t)(q0 + qt + fr) * C_ + hd;
            const unsigned short* qrl = qlo + base + (size_t)(q0 + qt + fr) * C_ + hd;
#pragma unroll
            for (int ks = 0; ks < 2; ++ks) {
                qh[ks] = *(const short8*)(qrh + ks * 32 + fq);
                ql[ks] = *(const short8*)(qrl + ks * 32 + fq);
            }
        }
        // ---- scores: 4 key-chunks of 64 ----
        for (int c = 0; c < 4; ++c) {
            {
                const unsigned short* sh_ = khi + base + (size_t)(c * 64 + key_l) * C_ + hd + cseg;
                const unsigned short* sl_ = klo + base + (size_t)(c * 64 + key_l) * C_ + hd + cseg;
                *(short8*)&Khi[key_l][cseg]     = *(const short8*)sh_;
                *(short8*)&Khi[key_l][cseg + 8] = *(const short8*)(sh_ + 8);
                *(short8*)&Klo[key_l][cseg]     = *(const short8*)sl_;
                *(short8*)&Klo[key_l][cseg + 8] = *(const short8*)(sl_ + 8);
            }
            __syncthreads();
            f32x4 sa[2];
            sa[0] = (f32x4){0.f, 0.f, 0.f, 0.f};
            sa[1] = (f32x4){0.f, 0.f, 0.f, 0.f};
#pragma unroll
            for (int ks = 0; ks < 2; ++ks) {
#pragma unroll
                for (int n = 0; n < 2; ++n) {
                    short8 bh = *(const short8*)&Khi[(nt0 + n) * 16 + fr][ks * 32 + fq];
                    short8 bl = *(const short8*)&Klo[(nt0 + n) * 16 + fr][ks * 32 + fq];
                    sa[n] = MFMA16(qh[ks], bh, sa[n]);
                    sa[n] = MFMA16(qh[ks], bl, sa[n]);
                    sa[n] = MFMA16(ql[ks], bh, sa[n]);
                }
            }
#pragma unroll
            for (int n = 0; n < 2; ++n)
#pragma unroll
                for (int r = 0; r < 4; ++r)
                    S[qt + quad * 4 + r][c * 64 + (nt0 + n) * 16 + fr] = sa[n][r] * 0.125f;
            __syncthreads();
        }
        // ---- softmax over 256 keys ----
        {
            float m = -3.402823466e38f;
#pragma unroll
            for (int j = 0; j < 32; ++j) m = fmaxf(m, S[sq][KK_(j)]);
            redm[sq][seg] = m;
            __syncthreads();
            float mm = redm[sq][0];
#pragma unroll
            for (int j = 1; j < 8; ++j) mm = fmaxf(mm, redm[sq][j]);
            float e[32];
            float sum = 0.f;
#pragma unroll
            for (int j = 0; j < 32; ++j) {
                e[j] = __expf(S[sq][KK_(j)] - mm);
                sum += e[j];
            }
            redl[sq][seg] = sum;
            __syncthreads();
            float tot = 0.f;
#pragma unroll
            for (int j = 0; j < 8; ++j) tot += redl[sq][j];
            float rl = 1.f / tot;
#pragma unroll
            for (int j = 0; j < 32; ++j) {
                float p = e[j] * rl;
                S[sq][KK_(j)] = p;
                avg[j] += p * (1.f / H_);
            }
            __syncthreads();
        }
        // ---- PV: 2 key-chunks of 128, V pre-transposed in global ----
        f32x4 ca[2];
        ca[0] = (f32x4){0.f, 0.f, 0.f, 0.f};
        ca[1] = (f32x4){0.f, 0.f, 0.f, 0.f};
        for (int c = 0; c < 2; ++c) {
            {
                const unsigned short* src = vt + base + (size_t)(hd + vrow) * N_ + c * 128 + vseg;
#pragma unroll
                for (int j = 0; j < 4; ++j)
                    *(short8*)&Vts[vrow][vseg + j * 8] = *(const short8*)(src + j * 8);
            }
            __syncthreads();
#pragma unroll
            for (int ks = 0; ks < 4; ++ks) {
                const float* pr = &S[qt + fr][c * 128 + ks * 32 + fq];
                float v[8];
                *(float4*)(v)     = *(const float4*)pr;
                *(float4*)(v + 4) = *(const float4*)(pr + 4);
                short8 pa;
                cvt8(v, pa);
#pragma unroll
                for (int n = 0; n < 2; ++n) {
                    short8 vb = *(const short8*)&Vts[(nt0 + n) * 16 + fr][ks * 32 + fq];
                    ca[n] = MFMA16(pa, vb, ca[n]);
                }
            }
            __syncthreads();
        }
        // ---- ctx store (bf16) ----
#pragma unroll
        for (int n = 0; n < 2; ++n)
#pragma unroll
            for (int r = 0; r < 4; ++r)
                ctxb[base + (size_t)(q0 + qt + quad * 4 + r) * C_ + hd + (nt0 + n) * 16 + fr] =
                    bf16_rne(ca[n][r]);
        __syncthreads();
    }
    // ---- attn_avg ----
    {
        float* dst = attn_avg + (size_t)bt * (N_ * N_) + (size_t)(q0 + sq) * N_;
#pragma unroll
        for (int j = 0; j < 32; ++j) dst[KK_(j)] = avg[j];
    }
#undef KK_
}

// ---------------------------------------------------------------------------
// LayerNorm(x + attn_out)
// ---------------------------------------------------------------------------
__global__ __launch_bounds__(256) void ln_kernel(
    const float* __restrict__ x, const float* __restrict__ ao,
    const float* __restrict__ gamma, const float* __restrict__ beta,
    float* __restrict__ out)
{
    __shared__ float r1[256], r2[256];
    int row = blockIdx.x, tid = threadIdx.x;
    const float4 xv = *(const float4*)(x + (size_t)row * C_ + tid * 4);
    const float4 av = *(const float4*)(ao + (size_t)row * C_ + tid * 4);
    float4 h = {xv.x + av.x, xv.y + av.y, xv.z + av.z, xv.w + av.w};
    float s = h.x + h.y + h.z + h.w;
    float s2 = h.x * h.x + h.y * h.y + h.z * h.z + h.w * h.w;
    r1[tid] = s; r2[tid] = s2;
    __syncthreads();
    for (int st = 128; st > 0; st >>= 1) {
        if (tid < st) { r1[tid] += r1[tid + st]; r2[tid] += r2[tid + st]; }
        __syncthreads();
    }
    float mu = r1[0] * (1.f / C_);
    float var = r2[0] * (1.f / C_) - mu * mu;
    float rs = rsqrtf(var + 1e-5f);
    float4 g = *(const float4*)(gamma + tid * 4);
    float4 b = *(const float4*)(beta + tid * 4);
    float4 o = {(h.x - mu) * rs * g.x + b.x,
                (h.y - mu) * rs * g.y + b.y,
                (h.z - mu) * rs * g.z + b.z,
                (h.w - mu) * rs * g.w + b.w};
    *(float4*)(out + (size_t)row * C_ + tid * 4) = o;
}

// ---------------------------------------------------------------------------
extern "C" void kernel_launch(void* const* d_in, const int* in_sizes, int n_in,
                              void* d_out, int out_size, void* d_ws, size_t ws_size,
                              hipStream_t stream)
{
    const float* x     = (const float*)d_in[0];
    const float* y     = (const float*)d_in[1];
    const float* q_e   = (const float*)d_in[3];
    const float* k_e   = (const float*)d_in[4];
    const float* dyn_w = (const float*)d_in[5];
    const float* dyn_b = (const float*)d_in[6];
    const float* v_w   = (const float*)d_in[7];
    const float* v_b   = (const float*)d_in[8];
    const float* in_w  = (const float*)d_in[9];
    const float* in_b  = (const float*)d_in[10];
    const float* out_w = (const float*)d_in[11];
    const float* out_b = (const float*)d_in[12];
    const float* gamma = (const float*)d_in[13];
    const float* beta  = (const float*)d_in[14];

    float* out      = (float*)d_out;
    float* attn_avg = (float*)d_out + (size_t)M_ * C_;

    float* ws = (float*)d_ws;
    size_t o = 0;
    const size_t MC = (size_t)M_ * C_;
    unsigned short* q_hi = (unsigned short*)(ws + o); o += MC / 2;
    unsigned short* q_lo = (unsigned short*)(ws + o); o += MC / 2;
    unsigned short* k_hi = (unsigned short*)(ws + o); o += MC / 2;
    unsigned short* k_lo = (unsigned short*)(ws + o); o += MC / 2;
    unsigned short* qa_hi = (unsigned short*)(ws + o); o += MC / 2;  // also ka_hi, vp_b
    unsigned short* qa_lo = (unsigned short*)(ws + o); o += MC / 2;  // also ka_lo, vt_b
    unsigned short* ctx_b = (unsigned short*)(ws + o); o += MC / 2;  // also xb (x in bf16)
    float* q_scale  = ws + o; o += (size_t)B_ * N_ * C_;
    float* k_scale  = ws + o; o += (size_t)B_ * N_ * C_;
    float* W_comb   = ws + o; o += (size_t)C_ * C_;
    unsigned short* w_hi   = (unsigned short*)(ws + o); o += (size_t)C_ * C_;      // wq+wk hi
    unsigned short* w_lo   = (unsigned short*)(ws + o); o += (size_t)C_ * C_;      // wq+wk lo
    unsigned short* Wc_b   = (unsigned short*)(ws + o); o += (size_t)C_ * C_ / 2;
    unsigned short* ow_b   = (unsigned short*)(ws + o); o += (size_t)C_ * C_ / 2;
    float* qe_sum   = ws + o; o += (size_t)K_ * C_;
    float* ke_sum   = ws + o; o += (size_t)K_ * C_;
    float* dyn      = ws + o; o += (size_t)B_ * N_ * K_;
    float* b_comb   = ws + o; o += C_;
    unsigned short* xb   = ctx_b;     // x as bf16; dead before attn writes ctx
    unsigned short* vp_b = qa_hi;     // dead after k-GEMM
    unsigned short* vt_b = qa_lo;     // dead after k-GEMM
    float* attn_out = (float*)q_hi;   // q_hi+q_lo region (MC floats) dead after attention

    const float* wv = in_w + 2 * C_ * C_;

    expert_sum_kernel<<<dim3(2 * K_ * C_ / 256), 256, 0, stream>>>(q_e, k_e, qe_sum, ke_sum);
    dyn_kernel<<<dim3(B_ * N_), 256, 0, stream>>>(y, dyn_w, dyn_b, dyn);
    scale_kernel<<<dim3(B_ * N_), 256, 0, stream>>>(dyn, qe_sum, ke_sum, q_scale, k_scale);
    bcomb_kernel<<<dim3(C_), 256, 0, stream>>>(wv, v_b, in_b + 2 * C_, b_comb);
    // W_comb = wv @ v_w (fp32, small)
    gemm_f32_nn<<<dim3(C_ / 128, C_ / 128), 256, 0, stream>>>(wv, v_w, W_comb, C_, C_, C_);
    // weight preps
    split_bf16_kernel<<<dim3(2 * C_ * C_ / 256), 256, 0, stream>>>(in_w, w_hi, w_lo, 2 * C_ * C_);
    cvt_bf16_kernel<<<dim3(C_ * C_ / 256), 256, 0, stream>>>(W_comb, Wc_b, C_ * C_);
    cvt_bf16_kernel<<<dim3(C_ * C_ / 256), 256, 0, stream>>>(out_w, ow_b, C_ * C_);
    // xb = bf16(x)   (into ctx_b region, dead before attn)
    cvt8_bf16_kernel<<<dim3(M_ * (C_ / 8) / 256), 256, 0, stream>>>(x, xb);
    // qa = split(x * q_scale); q = qa @ wq.T + bq
    scale_split_kernel<<<dim3(M_ * (C_ / 8) / 256), 256, 0, stream>>>(x, q_scale, qa_hi, qa_lo);
    gemm_mfma<3, 2><<<dim3(C_ / 128, M_ / 128), 256, 0, stream>>>(
        qa_hi, qa_lo, w_hi, w_lo, in_b, q_hi, q_lo);
    // ka = split(x * k_scale); k = ka @ wk.T + bk   (reuse qa buffers)
    scale_split_kernel<<<dim3(M_ * (C_ / 8) / 256), 256, 0, stream>>>(x, k_scale, qa_hi, qa_lo);
    gemm_mfma<3, 2><<<dim3(C_ / 128, M_ / 128), 256, 0, stream>>>(
        qa_hi, qa_lo, w_hi + C_ * C_, w_lo + C_ * C_, in_b + C_, k_hi, k_lo);
    // vp = xb @ W_comb.T + b_comb  -> bf16  (into qa_hi region)
    gemm_mfma<2, 1><<<dim3(C_ / 128, M_ / 128), 256, 0, stream>>>(
        xb, nullptr, Wc_b, nullptr, b_comb, vp_b, nullptr);
    // vt[bt][d][key] = vp transposed (into qa_lo region)
    vtrans_kernel<<<dim3(BT_ * 4 * 16), 256, 0, stream>>>(vp_b, vt_b);
    // attention
    attn_mfma_kernel<<<dim3(BT_ * (N_ / 32)), 256, 0, stream>>>(
        q_hi, q_lo, k_hi, k_lo, vt_b, ctx_b, attn_avg);
    // attn_out = ctx @ out_w.T + out_b   (into q_hi/q_lo region)
    gemm_mfma<2, 0><<<dim3(C_ / 128, M_ / 128), 256, 0, stream>>>(
        ctx_b, nullptr, ow_b, nullptr, out_b, attn_out, nullptr);
    // out = LN(x + attn_out)
    ln_kernel<<<dim3(M_), 256, 0, stream>>>(x, attn_out, gamma, beta, out);

    (void)in_sizes; (void)n_in; (void)out_size; (void)ws_size;
}